// Round 12
// baseline (579.381 us; speedup 1.0000x reference)
//
#include <hip/hip_runtime.h>
#include <math.h>

#define NN 50000
#define NE 800000

typedef short bf16x8 __attribute__((ext_vector_type(8)));
typedef float f32x4 __attribute__((ext_vector_type(4)));
typedef float f32x2 __attribute__((ext_vector_type(2)));

__device__ inline ushort f2bf(float f) {
    union { float f; uint u; } v; v.f = f;
    uint r = v.u + 0x7FFFu + ((v.u >> 16) & 1u);
    return (ushort)(r >> 16);
}
__device__ inline float bf2f(ushort h) {
    union { uint u; float f; } v; v.u = ((uint)h) << 16;
    return v.f;
}
// fp8 e4m3fn software codecs (bit-exact OCP e4m3fn incl. denormals)
__device__ inline uchar f2fp8(float f) {
    float a = fminf(fabsf(f), 448.f);
    union { float f; uint u; } v; v.f = a * 7.52316384526264e-37f;  // *2^-120
    uint r = (v.u + 0x7FFFFu + ((v.u >> 20) & 1u)) >> 20;           // RNE to e4m3 magnitude
    if (r > 0x7Eu) r = 0x7Eu;
    union { float f; uint u; } s; s.f = f;
    return (uchar)(r | ((s.u >> 31) << 7));
}
__device__ inline float fp8dec(uint b) {
    union { uint u; float f; } t; t.u = (b & 0x7Fu) << 20;
    union { float f; uint u; } o; o.f = t.f * 1.3292279957849159e36f;  // *2^120
    o.u |= (b & 0x80u) << 24;
    return o.f;
}
__device__ inline void acc_fp8x4(float* acc, uint u) {
#if __has_builtin(__builtin_amdgcn_cvt_pk_f32_fp8)
    f32x2 lo = __builtin_amdgcn_cvt_pk_f32_fp8((int)u, false);
    f32x2 hi = __builtin_amdgcn_cvt_pk_f32_fp8((int)u, true);
    acc[0] += lo[0]; acc[1] += lo[1]; acc[2] += hi[0]; acc[3] += hi[1];
#else
    acc[0] += fp8dec(u & 0xFFu);
    acc[1] += fp8dec((u >> 8) & 0xFFu);
    acc[2] += fp8dec((u >> 16) & 0xFFu);
    acc[3] += fp8dec(u >> 24);
#endif
}
__device__ inline uint pk2bf(float a, float b) {
    return (uint)f2bf(a) | ((uint)f2bf(b) << 16);
}
__device__ inline uint pk4f8(float a, float b, float c, float d) {
    return (uint)f2fp8(a) | ((uint)f2fp8(b) << 8) | ((uint)f2fp8(c) << 16) | ((uint)f2fp8(d) << 24);
}

// ---------------- CSR build ----------------

__global__ void count_edges_k(const int* __restrict__ edst, int* __restrict__ counts, int e) {
    int i = blockIdx.x * blockDim.x + threadIdx.x;
    if (i < e) atomicAdd(&counts[edst[i]], 1);
}

__global__ __launch_bounds__(1024) void scan1_k(const int* __restrict__ counts,
                                                int* __restrict__ row_start,
                                                int* __restrict__ bsum, int n) {
    __shared__ int sd[1024];
    int i = blockIdx.x * 1024 + threadIdx.x;
    int v = (i < n) ? counts[i] : 0;
    sd[threadIdx.x] = v;
    __syncthreads();
    for (int off = 1; off < 1024; off <<= 1) {
        int t = (threadIdx.x >= off) ? sd[threadIdx.x - off] : 0;
        __syncthreads();
        sd[threadIdx.x] += t;
        __syncthreads();
    }
    if (i < n) row_start[i] = sd[threadIdx.x] - v;
    if (threadIdx.x == 1023) bsum[blockIdx.x] = sd[1023];
}

__global__ void scan2_k(int* __restrict__ bsum, int nb) {
    int lane = threadIdx.x;
    int v = (lane < nb) ? bsum[lane] : 0;
    int orig = v;
    for (int off = 1; off < 64; off <<= 1) {
        int t = __shfl_up(v, off);
        if (lane >= off) v += t;
    }
    if (lane < nb) bsum[lane] = v - orig;
}

__global__ void scan3_k(const int* __restrict__ counts, const int* __restrict__ bsum,
                        int* __restrict__ row_start, int* __restrict__ cursor,
                        float* __restrict__ inv_deg, int n, int e) {
    int i = blockIdx.x * blockDim.x + threadIdx.x;
    if (i < n) {
        int rs = row_start[i] + bsum[i >> 10];
        row_start[i] = rs;
        cursor[i] = rs;
        inv_deg[i] = 1.0f / fmaxf((float)counts[i], 1.0f);
        if (i == 0) row_start[n] = e;
    }
}

__global__ void fill_csr_k(const int* __restrict__ esrc, const int* __restrict__ edst,
                           int* __restrict__ cursor, int* __restrict__ csr_src, int e) {
    int i = blockIdx.x * blockDim.x + threadIdx.x;
    if (i < e) {
        int pos = atomicAdd(&cursor[edst[i]], 1);
        csr_src[pos] = esrc[i];
    }
}

// ---------------- weight prep (all 4 fused) ----------------

struct PrepArg { const float* W1; const float* W2; ushort* Wt; int K; int M; };

__global__ void prep_w4_k(PrepArg p0, PrepArg p1, PrepArg p2, PrepArg p3) {
    PrepArg P = (blockIdx.y == 0) ? p0 : (blockIdx.y == 1) ? p1 : (blockIdx.y == 2) ? p2 : p3;
    int i = blockIdx.x * blockDim.x + threadIdx.x;
    int tot = 2 * P.M * P.K;
    if (i >= tot) return;
    int c = i / P.K, k = i - c * P.K;
    float v = (c < P.M) ? P.W1[(size_t)k * P.M + c] : P.W2[(size_t)k * P.M + (c - P.M)];
    P.Wt[i] = f2bf(v);
}

// ---------------- MFMA GEMM: 128x128 block tile, 4 waves of 64x64 -------------------
// Swapped-operand MFMA (lane = 1 row x 4 consecutive cols). Single-buffer LDS 20.5KB.
// cols<M -> V8 (fp8, row stride ldv), cols>=M -> R (bf16, row stride ldr)

struct GArg { const void* A; const ushort* Wt; uchar* V8; ushort* R; };
template<int NY> struct GArgs { GArg a[NY]; };

template<bool A_FP32, int NY>
__global__ __launch_bounds__(256) void gemm_mfma_k(GArgs<NY> P, int K, int M,
                                                   int ldv, int ldr, int n) {
    __shared__ __align__(16) uchar smem[20480];  // As[128][40] + Bs[128][40]
    ushort* As = (ushort*)smem;
    ushort* Bs = As + 128 * 40;
    const GArg& G = P.a[blockIdx.z];
    const void* __restrict__ Av = G.A;
    const ushort* __restrict__ Wt = G.Wt;

    int tid = threadIdx.x;
    int row0 = blockIdx.x * 128;
    int col0 = blockIdx.y * 128;
    int lane = tid & 63, wid = tid >> 6;
    int wm = wid & 1, wn = wid >> 1;
    int lrow = lane & 15, lko = (lane >> 4) * 8;

    f32x4 acc[4][4];
    #pragma unroll
    for (int i = 0; i < 4; ++i)
        #pragma unroll
        for (int j = 0; j < 4; ++j)
            acc[i][j] = (f32x4){0.f, 0.f, 0.f, 0.f};

    float4 fA[4];
    uint4 uA[2], uB[2];

    auto LOAD = [&](int it) {
        int kc = it << 5;
        if constexpr (A_FP32) {
            const float* A = (const float*)Av;
            #pragma unroll
            for (int p = 0; p < 4; ++p) {
                int l = tid + p * 256, r = l >> 3, s = l & 7;
                int rg = row0 + r;
                fA[p] = (rg < n) ? *(const float4*)(A + (size_t)rg * K + kc + s * 4)
                                 : make_float4(0.f, 0.f, 0.f, 0.f);
            }
        } else {
            const ushort* A = (const ushort*)Av;
            #pragma unroll
            for (int p = 0; p < 2; ++p) {
                int l = tid + p * 256, r = l >> 2, s = l & 3;
                int rg = row0 + r;
                uA[p] = (rg < n) ? *(const uint4*)(A + (size_t)rg * K + kc + s * 8)
                                 : make_uint4(0u, 0u, 0u, 0u);
            }
        }
        #pragma unroll
        for (int p = 0; p < 2; ++p) {
            int l = tid + p * 256, c = l >> 2, s = l & 3;
            uB[p] = *(const uint4*)(Wt + (size_t)(col0 + c) * K + kc + s * 8);
        }
    };
    auto STORE_LDS = [&]() {
        if constexpr (A_FP32) {
            #pragma unroll
            for (int p = 0; p < 4; ++p) {
                int l = tid + p * 256, r = l >> 3, s = l & 7;
                *(uint2*)(&As[r * 40 + s * 4]) =
                    make_uint2(pk2bf(fA[p].x, fA[p].y), pk2bf(fA[p].z, fA[p].w));
            }
        } else {
            #pragma unroll
            for (int p = 0; p < 2; ++p) {
                int l = tid + p * 256, r = l >> 2, s = l & 3;
                *(uint4*)(&As[r * 40 + s * 8]) = uA[p];
            }
        }
        #pragma unroll
        for (int p = 0; p < 2; ++p) {
            int l = tid + p * 256, c = l >> 2, s = l & 3;
            *(uint4*)(&Bs[c * 40 + s * 8]) = uB[p];
        }
    };

    const int nIt = K >> 5;
    LOAD(0);
    for (int it = 0; it < nIt; ++it) {
        __syncthreads();
        STORE_LDS();
        __syncthreads();
        if (it + 1 < nIt) LOAD(it + 1);

        bf16x8 af[4], bfr[4];
        #pragma unroll
        for (int i = 0; i < 4; ++i)
            af[i] = *(const bf16x8*)(&As[(wm * 64 + i * 16 + lrow) * 40 + lko]);
        #pragma unroll
        for (int j = 0; j < 4; ++j)
            bfr[j] = *(const bf16x8*)(&Bs[(wn * 64 + j * 16 + lrow) * 40 + lko]);
        #pragma unroll
        for (int i = 0; i < 4; ++i)
            #pragma unroll
            for (int j = 0; j < 4; ++j)
                acc[i][j] = __builtin_amdgcn_mfma_f32_16x16x32_bf16(bfr[j], af[i], acc[i][j], 0, 0, 0);
    }

    // -------- packed-dword epilogue through LDS --------
    if (col0 + 128 <= M) {
        // pure fp8: C8dw[128][33] = 16896B (fits 20480)
        uint* C8 = (uint*)smem;
        __syncthreads();
        #pragma unroll
        for (int i = 0; i < 4; ++i) {
            int m = wm * 64 + i * 16 + (lane & 15);
            #pragma unroll
            for (int j = 0; j < 4; ++j) {
                int dc = wn * 16 + j * 4 + (lane >> 4);
                C8[m * 33 + dc] = pk4f8(acc[i][j][0], acc[i][j][1], acc[i][j][2], acc[i][j][3]);
            }
        }
        __syncthreads();
        int row = tid >> 1, seg = tid & 1;
        if (row0 + row < n) {
            uchar* g = G.V8 + (size_t)(row0 + row) * ldv + col0 + seg * 64;
            #pragma unroll
            for (int t = 0; t < 4; ++t) {
                int b = row * 33 + seg * 16 + t * 4;
                *(uint4*)(g + t * 16) = make_uint4(C8[b], C8[b + 1], C8[b + 2], C8[b + 3]);
            }
        }
    } else if (col0 >= M) {
        // pure bf16: two passes of C16dw[64][65] = 16640B
        uint* C16 = (uint*)smem;
        #pragma unroll
        for (int h = 0; h < 2; ++h) {
            __syncthreads();
            if (wm == h) {
                #pragma unroll
                for (int i = 0; i < 4; ++i) {
                    int lm = i * 16 + (lane & 15);
                    #pragma unroll
                    for (int j = 0; j < 4; ++j) {
                        int dc = wn * 32 + j * 8 + (lane >> 4) * 2;
                        C16[lm * 65 + dc]     = pk2bf(acc[i][j][0], acc[i][j][1]);
                        C16[lm * 65 + dc + 1] = pk2bf(acc[i][j][2], acc[i][j][3]);
                    }
                }
            }
            __syncthreads();
            int row = tid >> 2, seg = tid & 3;
            int grow = row0 + h * 64 + row;
            if (grow < n) {
                ushort* g = G.R + (size_t)grow * ldr + (col0 - M) + seg * 32;
                #pragma unroll
                for (int t = 0; t < 4; ++t) {
                    int b = row * 65 + seg * 16 + t * 4;
                    *(uint4*)(g + t * 8) = make_uint4(C16[b], C16[b + 1], C16[b + 2], C16[b + 3]);
                }
            }
        }
    } else {
        // mixed (M == 64): two passes; wn=0 -> fp8 C8dw[64][17]; wn=1 -> bf16 C16dw[64][33]
        uint* C8  = (uint*)smem;             // 4352B
        uint* C16 = (uint*)(smem + 4608);    // 8448B
        #pragma unroll
        for (int h = 0; h < 2; ++h) {
            __syncthreads();
            if (wm == h) {
                #pragma unroll
                for (int i = 0; i < 4; ++i) {
                    int lm = i * 16 + (lane & 15);
                    #pragma unroll
                    for (int j = 0; j < 4; ++j) {
                        if (wn == 0) {
                            int dc = j * 4 + (lane >> 4);
                            C8[lm * 17 + dc] = pk4f8(acc[i][j][0], acc[i][j][1], acc[i][j][2], acc[i][j][3]);
                        } else {
                            int dc = j * 8 + (lane >> 4) * 2;
                            C16[lm * 33 + dc]     = pk2bf(acc[i][j][0], acc[i][j][1]);
                            C16[lm * 33 + dc + 1] = pk2bf(acc[i][j][2], acc[i][j][3]);
                        }
                    }
                }
            }
            __syncthreads();
            int row = tid >> 2, seg = tid & 3;
            int grow = row0 + h * 64 + row;
            if (grow < n) {
                int b8 = row * 17 + seg * 4;
                *(uint4*)(G.V8 + (size_t)grow * ldv + seg * 16) =
                    make_uint4(C8[b8], C8[b8 + 1], C8[b8 + 2], C8[b8 + 3]);
                ushort* g = G.R + (size_t)grow * ldr + seg * 16;
                #pragma unroll
                for (int t = 0; t < 2; ++t) {
                    int b = row * 33 + seg * 8 + t * 4;
                    *(uint4*)(g + t * 8) = make_uint4(C16[b], C16[b + 1], C16[b + 2], C16[b + 3]);
                }
            }
        }
    }
}

// ---------------- fused agg, 512B interleaved rows (input: NZ=4, mid: NZ=2) ----------

struct Bias4 { const float* b[4]; };

template<int NZ, int U>
__global__ __launch_bounds__(256) void agg_f512_k(const uchar* __restrict__ V8,
                                                  const ushort* __restrict__ R,
                                                  Bias4 B,
                                                  const float* __restrict__ inv_deg,
                                                  const int* __restrict__ row_start,
                                                  const int* __restrict__ csr_src,
                                                  ushort* __restrict__ xkout,
                                                  size_t tstride, int n) {
    constexpr int LPZ = 64 / NZ;
    int wid  = (blockIdx.x * blockDim.x + threadIdx.x) >> 6;
    int lane = threadIdx.x & 63;
    if (wid >= n) return;
    int dst = wid;
    int c0 = (lane & (LPZ - 1)) * 8;
    const float* bp = B.b[lane / LPZ] + c0;
    int off8 = lane * 8;

    float acc[8];
    #pragma unroll
    for (int q = 0; q < 8; ++q) acc[q] = 0.f;

    int s = row_start[dst], e = row_start[dst + 1];
    for (int g = s; g < e; g += U) {
        int idx[U];
        #pragma unroll
        for (int u = 0; u < U; ++u)
            idx[u] = (g + u < e) ? csr_src[g + u] : -1;
        uint2 d[U];
        #pragma unroll
        for (int u = 0; u < U; ++u) {
            d[u] = make_uint2(0u, 0u);
            if (idx[u] >= 0) d[u] = *(const uint2*)(V8 + (size_t)idx[u] * 512 + off8);
        }
        #pragma unroll
        for (int u = 0; u < U; ++u) {
            acc_fp8x4(acc,     d[u].x);
            acc_fp8x4(acc + 4, d[u].y);
        }
    }

    float inv = inv_deg[dst];
    float r[8];
    uint4 rr = *(const uint4*)(R + (size_t)dst * 512 + off8);
    uint rw[4] = {rr.x, rr.y, rr.z, rr.w};
    #pragma unroll
    for (int q = 0; q < 8; ++q) r[q] = acc[q] * inv + bp[q];
    #pragma unroll
    for (int p = 0; p < 4; ++p) {
        r[p * 2 + 0] += bf2f((ushort)(rw[p] & 0xFFFF));
        r[p * 2 + 1] += bf2f((ushort)(rw[p] >> 16));
    }
    #pragma unroll
    for (int q = 0; q < 8; ++q) r[q] = fmaxf(r[q], 0.f);   // relu

    uint4 o;
    o.x = pk2bf(r[0], r[1]); o.y = pk2bf(r[2], r[3]);
    o.z = pk2bf(r[4], r[5]); o.w = pk2bf(r[6], r[7]);
    *(uint4*)(xkout + (size_t)(lane >> 5) * tstride + (size_t)dst * 256 + (lane & 31) * 8) = o;
}

// ---------------- fused agg, 128B interleaved rows (out layer + head agg) ------------

template<int ACT, bool WF8, int U>
__global__ __launch_bounds__(256) void agg_f128_k(const uchar* __restrict__ V8,
                                                  const ushort* __restrict__ R,
                                                  const float* __restrict__ bias,
                                                  const float* __restrict__ inv_deg,
                                                  const int* __restrict__ row_start,
                                                  const int* __restrict__ csr_src,
                                                  ushort* __restrict__ outb, size_t tstride,
                                                  uchar* __restrict__ out8,
                                                  int n) {
    int wid  = (blockIdx.x * blockDim.x + threadIdx.x) >> 6;
    int lane = threadIdx.x & 63;
    if (wid >= n) return;
    int dst   = wid;
    int sub   = lane & 15;
    int eslot = lane >> 4;
    int task  = sub >> 3;
    int c0    = (sub & 7) * 8;

    float acc[8];
    #pragma unroll
    for (int q = 0; q < 8; ++q) acc[q] = 0.f;

    int s = row_start[dst], e = row_start[dst + 1];
    for (int g = s; g < e; g += 4 * U) {
        int idx[U];
        #pragma unroll
        for (int u = 0; u < U; ++u) {
            int t = g + u * 4 + eslot;
            idx[u] = (t < e) ? csr_src[t] : -1;
        }
        uint2 d[U];
        #pragma unroll
        for (int u = 0; u < U; ++u) {
            d[u] = make_uint2(0u, 0u);
            if (idx[u] >= 0) d[u] = *(const uint2*)(V8 + (size_t)idx[u] * 128 + sub * 8);
        }
        #pragma unroll
        for (int u = 0; u < U; ++u) {
            acc_fp8x4(acc,     d[u].x);
            acc_fp8x4(acc + 4, d[u].y);
        }
    }

    #pragma unroll
    for (int mask = 16; mask < 64; mask <<= 1)
        #pragma unroll
        for (int q = 0; q < 8; ++q)
            acc[q] += __shfl_xor(acc[q], mask);

    if (eslot == 0) {
        float inv = inv_deg[dst];
        float r[8];
        #pragma unroll
        for (int q = 0; q < 8; ++q) r[q] = acc[q] * inv;
        if (bias) {
            #pragma unroll
            for (int q = 0; q < 8; ++q) r[q] += bias[c0 + q];
        }
        if (R) {
            uint4 rr = *(const uint4*)(R + (size_t)dst * 128 + sub * 8);
            uint rw[4] = {rr.x, rr.y, rr.z, rr.w};
            #pragma unroll
            for (int p = 0; p < 4; ++p) {
                r[p * 2 + 0] += bf2f((ushort)(rw[p] & 0xFFFF));
                r[p * 2 + 1] += bf2f((ushort)(rw[p] >> 16));
            }
        }
        #pragma unroll
        for (int q = 0; q < 8; ++q) {
            if constexpr (ACT == 2) r[q] = 1.f / (1.f + expf(-r[q]));
        }
        uint4 o;
        o.x = pk2bf(r[0], r[1]); o.y = pk2bf(r[2], r[3]);
        o.z = pk2bf(r[4], r[5]); o.w = pk2bf(r[6], r[7]);
        *(uint4*)(outb + (size_t)task * tstride + (size_t)dst * 64 + c0) = o;
        if constexpr (WF8) {
            uint2 o8;
            o8.x = pk4f8(r[0], r[1], r[2], r[3]);
            o8.y = pk4f8(r[4], r[5], r[6], r[7]);
            *(uint2*)(out8 + (size_t)dst * 128 + sub * 8) = o8;
        }
    }
}

// ---------------- heads + cross-entropy (spill-free, both tasks via blockIdx.y) ------

template<int C>
__device__ inline float ce_from_z(float* z, int label) {
    float m = -1e30f;
    #pragma unroll
    for (int c = 0; c < C; ++c) { z[c] = 1.f / (1.f + expf(-z[c])); m = fmaxf(m, z[c]); }
    float ssum = 0.f, zl = 0.f;
    #pragma unroll
    for (int c = 0; c < C; ++c) { ssum += expf(z[c] - m); if (c == label) zl = z[c]; }
    return (logf(ssum) + m) - zl;
}

__global__ __launch_bounds__(256) void head_ce_k(const ushort* __restrict__ Ah,
                                                 const ushort* __restrict__ hk,
                                                 const float* __restrict__ Wl1, const float* __restrict__ b1, const float* __restrict__ Wr1,
                                                 const float* __restrict__ Wl2, const float* __restrict__ b2, const float* __restrict__ Wr2,
                                                 const float* __restrict__ Wl3, const float* __restrict__ b3, const float* __restrict__ Wr3,
                                                 const int* __restrict__ yv,
                                                 float* __restrict__ loss_acc, int n) {
    int ty = blockIdx.y;
    int nidx = blockIdx.x * blockDim.x + threadIdx.x;
    Wl1 += ty * 64 * 12; b1 += ty * 12; Wr1 += ty * 64 * 12;
    Wl2 += ty * 64 * 8;  b2 += ty * 8;  Wr2 += ty * 64 * 8;
    Wl3 += ty * 64 * 5;  b3 += ty * 5;  Wr3 += ty * 64 * 5;
    float lsum = 0.f;
    if (nidx < n) {
        float z0[12], z1[8], z2[5];
        #pragma unroll
        for (int c = 0; c < 12; ++c) z0[c] = b1[c];
        #pragma unroll
        for (int c = 0; c < 8; ++c) z1[c] = b2[c];
        #pragma unroll
        for (int c = 0; c < 5; ++c) z2[c] = b3[c];

        const ushort* ap = Ah + ((size_t)ty * NN + nidx) * 64;
        const ushort* hp = hk + ((size_t)ty * NN + nidx) * 64;
        for (int d8 = 0; d8 < 64; d8 += 8) {
            uint4 ua = *(const uint4*)(ap + d8);
            uint4 uh = *(const uint4*)(hp + d8);
            uint aw[4] = {ua.x, ua.y, ua.z, ua.w};
            uint hw[4] = {uh.x, uh.y, uh.z, uh.w};
            #pragma unroll
            for (int p = 0; p < 4; ++p) {
                #pragma unroll
                for (int half = 0; half < 2; ++half) {
                    int d = d8 + p * 2 + half;
                    float av = bf2f((ushort)(half ? (aw[p] >> 16) : (aw[p] & 0xFFFF)));
                    float hv = bf2f((ushort)(half ? (hw[p] >> 16) : (hw[p] & 0xFFFF)));
                    #pragma unroll
                    for (int c = 0; c < 12; ++c)
                        z0[c] = fmaf(av, Wl1[d * 12 + c], fmaf(hv, Wr1[d * 12 + c], z0[c]));
                    #pragma unroll
                    for (int c = 0; c < 8; ++c)
                        z1[c] = fmaf(av, Wl2[d * 8 + c], fmaf(hv, Wr2[d * 8 + c], z1[c]));
                    #pragma unroll
                    for (int c = 0; c < 5; ++c)
                        z2[c] = fmaf(av, Wl3[d * 5 + c], fmaf(hv, Wr3[d * 5 + c], z2[c]));
                }
            }
        }
        const int* yp = yv + ((size_t)ty * NN + nidx) * 3;
        lsum  = ce_from_z<12>(z0, yp[0]);
        lsum += ce_from_z<8 >(z1, yp[1]);
        lsum += ce_from_z<5 >(z2, yp[2]);
    }
    for (int off = 32; off > 0; off >>= 1) lsum += __shfl_down(lsum, off);
    __shared__ float ssum[4];
    int wv = threadIdx.x >> 6, ln = threadIdx.x & 63;
    if (ln == 0) ssum[wv] = lsum;
    __syncthreads();
    if (threadIdx.x == 0) atomicAdd(loss_acc, ssum[0] + ssum[1] + ssum[2] + ssum[3]);
}

__global__ void finalize_k(const float* __restrict__ loss_acc, float* __restrict__ out, int n) {
    out[0] = loss_acc[0] * (1.0f / (float)n);
}

// ---------------- host ----------------

extern "C" void kernel_launch(void* const* d_in, const int* in_sizes, int n_in,
                              void* d_out, int out_size, void* d_ws, size_t ws_size,
                              hipStream_t stream) {
    const float* X    = (const float*)d_in[0];
    const int*   esrc = (const int*)d_in[1];
    const int*   edst = (const int*)d_in[2];
    const int*   y    = (const int*)d_in[3];
    const float* Wl_i[2] = {(const float*)d_in[4], (const float*)d_in[7]};
    const float* bl_i[2] = {(const float*)d_in[5], (const float*)d_in[8]};
    const float* Wr_i[2] = {(const float*)d_in[6], (const float*)d_in[9]};
    const float* Wl_m = (const float*)d_in[10], *bl_m = (const float*)d_in[11], *Wr_m = (const float*)d_in[12];
    const float* Wl_o = (const float*)d_in[13], *bl_o = (const float*)d_in[14], *Wr_o = (const float*)d_in[15];
    const float* Wl_t1 = (const float*)d_in[16], *bl_t1 = (const float*)d_in[17], *Wr_t1 = (const float*)d_in[18];
    const float* Wl_t2 = (const float*)d_in[19], *bl_t2 = (const float*)d_in[20], *Wr_t2 = (const float*)d_in[21];
    const float* Wl_t3 = (const float*)d_in[22], *bl_t3 = (const float*)d_in[23], *Wr_t3 = (const float*)d_in[24];

    const int N = NN, E = NE;
    char* p = (char*)d_ws;
    auto alloc = [&](size_t bytes) -> char* {
        char* r = p;
        p += (bytes + 255) & ~(size_t)255;
        return r;
    };
    int*    counts    = (int*)alloc((size_t)N * 4);
    int*    row_start = (int*)alloc((size_t)(N + 1) * 4);
    int*    cursor    = (int*)alloc((size_t)N * 4);
    int*    bsum      = (int*)alloc(64 * 4);
    int*    csr_src   = (int*)alloc((size_t)E * 4);
    float*  inv_deg   = (float*)alloc((size_t)N * 4);
    float*  loss_acc  = (float*)alloc(256);
    uchar*  V8i  = (uchar*)alloc((size_t)N * 512);            // [n][4*128] fp8
    ushort* Ri   = (ushort*)alloc((size_t)N * 512 * 2);       // [n][4*128] bf16
    uchar*  V8m  = (uchar*)alloc((size_t)N * 512);            // [n][2*256] fp8
    ushort* Rm   = (ushort*)alloc((size_t)N * 512 * 2);       // [n][2*256] bf16
    uchar*  V8o  = (uchar*)alloc((size_t)N * 128);            // [n][2*64] fp8
    ushort* Ro   = (ushort*)alloc((size_t)N * 128 * 2);       // [n][2*64] bf16
    ushort* xk   = (ushort*)alloc((size_t)2 * N * 256 * 2);   // [2][n][256] bf16
    ushort* hk   = (ushort*)alloc((size_t)2 * N * 64 * 2);    // [2][n][64] bf16
    uchar*  hk8  = (uchar*)alloc((size_t)N * 128);            // [n][2*64] fp8
    ushort* Ah   = (ushort*)alloc((size_t)2 * N * 64 * 2);    // [2][n][64] bf16
    ushort* Wt_i0 = (ushort*)alloc((size_t)256 * 128 * 2);
    ushort* Wt_i1 = (ushort*)alloc((size_t)256 * 128 * 2);
    ushort* Wt_m  = (ushort*)alloc((size_t)512 * 256 * 2);
    ushort* Wt_o  = (ushort*)alloc((size_t)128 * 256 * 2);

    hipMemsetAsync(counts, 0, (size_t)N * 4, stream);
    hipMemsetAsync(loss_acc, 0, 4, stream);
    count_edges_k<<<(E + 255) / 256, 256, 0, stream>>>(edst, counts, E);
    const int NB = (N + 1023) / 1024;
    scan1_k<<<NB, 1024, 0, stream>>>(counts, row_start, bsum, N);
    scan2_k<<<1, 64, 0, stream>>>(bsum, NB);
    scan3_k<<<(N + 255) / 256, 256, 0, stream>>>(counts, bsum, row_start, cursor, inv_deg, N, E);
    fill_csr_k<<<(E + 255) / 256, 256, 0, stream>>>(esrc, edst, cursor, csr_src, E);

    {
        PrepArg p0 = {Wl_i[0], Wr_i[0], Wt_i0, 128, 128};
        PrepArg p1 = {Wl_i[1], Wr_i[1], Wt_i1, 128, 128};
        PrepArg p2 = {Wl_m, Wr_m, Wt_m, 256, 256};
        PrepArg p3 = {Wl_o, Wr_o, Wt_o, 256, 64};
        prep_w4_k<<<dim3(512, 4), 256, 0, stream>>>(p0, p1, p2, p3);
    }

    const int RB2 = (N + 127) / 128;   // 391 row blocks (128-row tile)
    const int AGB = (N + 3) / 4;
    const ushort* Wt_i[2] = {Wt_i0, Wt_i1};
    const size_t TSX = (size_t)N * 256;
    const size_t TSH = (size_t)N * 64;

    // ---- stage A: input GEMMs, all 4 (k,ch), interleaved epilogue ----
    {
        GArgs<4> P;
        for (int z = 0; z < 4; ++z)
            P.a[z] = {X + (size_t)z * N * 128, Wt_i[z & 1], V8i + z * 128, Ri + z * 128};
        gemm_mfma_k<true, 4><<<dim3(RB2, 2, 4), 256, 0, stream>>>(P, 128, 128, 512, 512, N);
    }
    // ---- stage B: fused input agg ----
    {
        Bias4 B = {{bl_i[0], bl_i[1], bl_i[0], bl_i[1]}};
        agg_f512_k<4, 4><<<AGB, 256, 0, stream>>>(V8i, Ri, B, inv_deg, row_start, csr_src,
                                                  xk, TSX, N);
    }
    // ---- stage C: mid GEMMs, both tasks ----
    {
        GArgs<2> P;
        for (int k = 0; k < 2; ++k)
            P.a[k] = {xk + (size_t)k * TSX, Wt_m, V8m + k * 256, Rm + k * 256};
        gemm_mfma_k<false, 2><<<dim3(RB2, 4, 2), 256, 0, stream>>>(P, 256, 256, 512, 512, N);
    }
    // ---- stage D: fused mid agg ----
    {
        Bias4 B = {{bl_m, bl_m, nullptr, nullptr}};
        agg_f512_k<2, 4><<<AGB, 256, 0, stream>>>(V8m, Rm, B, inv_deg, row_start, csr_src,
                                                  xk, TSX, N);
    }
    // ---- stage E: out GEMMs ----
    {
        GArgs<2> P;
        for (int k = 0; k < 2; ++k)
            P.a[k] = {xk + (size_t)k * TSX, Wt_o, V8o + k * 64, Ro + k * 64};
        gemm_mfma_k<false, 2><<<dim3(RB2, 1, 2), 256, 0, stream>>>(P, 256, 64, 128, 128, N);
    }
    // ---- stage F: fused out agg (sigmoid) -> hk, hk8 ----
    agg_f128_k<2, true, 2><<<AGB, 256, 0, stream>>>(V8o, Ro, bl_o, inv_deg, row_start, csr_src,
                                                    hk, TSH, hk8, N);
    // ---- stage G: fused head agg (mean of hk) -> Ah ----
    agg_f128_k<0, false, 2><<<AGB, 256, 0, stream>>>(hk8, nullptr, nullptr, inv_deg, row_start, csr_src,
                                                     Ah, TSH, nullptr, N);
    // ---- stage H: heads + CE, both tasks ----
    head_ce_k<<<dim3((N + 255) / 256, 2), 256, 0, stream>>>(Ah, hk,
        Wl_t1, bl_t1, Wr_t1, Wl_t2, bl_t2, Wr_t2, Wl_t3, bl_t3, Wr_t3,
        y, loss_acc, N);

    finalize_k<<<1, 1, 0, stream>>>(loss_acc, (float*)d_out, N);
}

// Round 13
// 490.022 us; speedup vs baseline: 1.1824x; 1.1824x over previous
//
#include <hip/hip_runtime.h>
#include <math.h>

#define NN 50000
#define NE 800000

typedef short bf16x8 __attribute__((ext_vector_type(8)));
typedef float f32x4 __attribute__((ext_vector_type(4)));
typedef float f32x2 __attribute__((ext_vector_type(2)));

__device__ inline ushort f2bf(float f) {
    union { float f; uint u; } v; v.f = f;
    uint r = v.u + 0x7FFFu + ((v.u >> 16) & 1u);
    return (ushort)(r >> 16);
}
__device__ inline float bf2f(ushort h) {
    union { uint u; float f; } v; v.u = ((uint)h) << 16;
    return v.f;
}
// fp8 e4m3fn software codecs (bit-exact OCP e4m3fn incl. denormals)
__device__ inline uchar f2fp8(float f) {
    float a = fminf(fabsf(f), 448.f);
    union { float f; uint u; } v; v.f = a * 7.52316384526264e-37f;  // *2^-120
    uint r = (v.u + 0x7FFFFu + ((v.u >> 20) & 1u)) >> 20;           // RNE to e4m3 magnitude
    if (r > 0x7Eu) r = 0x7Eu;
    union { float f; uint u; } s; s.f = f;
    return (uchar)(r | ((s.u >> 31) << 7));
}
__device__ inline float fp8dec(uint b) {
    union { uint u; float f; } t; t.u = (b & 0x7Fu) << 20;
    union { float f; uint u; } o; o.f = t.f * 1.3292279957849159e36f;  // *2^120
    o.u |= (b & 0x80u) << 24;
    return o.f;
}
__device__ inline void acc_fp8x4(float* acc, uint u) {
#if __has_builtin(__builtin_amdgcn_cvt_pk_f32_fp8)
    f32x2 lo = __builtin_amdgcn_cvt_pk_f32_fp8((int)u, false);
    f32x2 hi = __builtin_amdgcn_cvt_pk_f32_fp8((int)u, true);
    acc[0] += lo[0]; acc[1] += lo[1]; acc[2] += hi[0]; acc[3] += hi[1];
#else
    acc[0] += fp8dec(u & 0xFFu);
    acc[1] += fp8dec((u >> 8) & 0xFFu);
    acc[2] += fp8dec((u >> 16) & 0xFFu);
    acc[3] += fp8dec(u >> 24);
#endif
}
__device__ inline uint pk2bf(float a, float b) {
    return (uint)f2bf(a) | ((uint)f2bf(b) << 16);
}
__device__ inline uint pk4f8(float a, float b, float c, float d) {
    return (uint)f2fp8(a) | ((uint)f2fp8(b) << 8) | ((uint)f2fp8(c) << 16) | ((uint)f2fp8(d) << 24);
}

// ---------------- CSR build ----------------

__global__ void count_edges_k(const int* __restrict__ edst, int* __restrict__ counts, int e) {
    int i = blockIdx.x * blockDim.x + threadIdx.x;
    if (i < e) atomicAdd(&counts[edst[i]], 1);
}

__global__ __launch_bounds__(1024) void scan1_k(const int* __restrict__ counts,
                                                int* __restrict__ row_start,
                                                int* __restrict__ bsum, int n) {
    __shared__ int sd[1024];
    int i = blockIdx.x * 1024 + threadIdx.x;
    int v = (i < n) ? counts[i] : 0;
    sd[threadIdx.x] = v;
    __syncthreads();
    for (int off = 1; off < 1024; off <<= 1) {
        int t = (threadIdx.x >= off) ? sd[threadIdx.x - off] : 0;
        __syncthreads();
        sd[threadIdx.x] += t;
        __syncthreads();
    }
    if (i < n) row_start[i] = sd[threadIdx.x] - v;
    if (threadIdx.x == 1023) bsum[blockIdx.x] = sd[1023];
}

__global__ void scan2_k(int* __restrict__ bsum, int nb) {
    int lane = threadIdx.x;
    int v = (lane < nb) ? bsum[lane] : 0;
    int orig = v;
    for (int off = 1; off < 64; off <<= 1) {
        int t = __shfl_up(v, off);
        if (lane >= off) v += t;
    }
    if (lane < nb) bsum[lane] = v - orig;
}

__global__ void scan3_k(const int* __restrict__ counts, const int* __restrict__ bsum,
                        int* __restrict__ row_start, int* __restrict__ cursor,
                        float* __restrict__ inv_deg, int n, int e) {
    int i = blockIdx.x * blockDim.x + threadIdx.x;
    if (i < n) {
        int rs = row_start[i] + bsum[i >> 10];
        row_start[i] = rs;
        cursor[i] = rs;
        inv_deg[i] = 1.0f / fmaxf((float)counts[i], 1.0f);
        if (i == 0) row_start[n] = e;
    }
}

__global__ void fill_csr_k(const int* __restrict__ esrc, const int* __restrict__ edst,
                           int* __restrict__ cursor, int* __restrict__ csr_src, int e) {
    int i = blockIdx.x * blockDim.x + threadIdx.x;
    if (i < e) {
        int pos = atomicAdd(&cursor[edst[i]], 1);
        csr_src[pos] = esrc[i];
    }
}

// ---------------- weight prep (all 4 fused) ----------------

struct PrepArg { const float* W1; const float* W2; ushort* Wt; int K; int M; };

__global__ void prep_w4_k(PrepArg p0, PrepArg p1, PrepArg p2, PrepArg p3) {
    PrepArg P = (blockIdx.y == 0) ? p0 : (blockIdx.y == 1) ? p1 : (blockIdx.y == 2) ? p2 : p3;
    int i = blockIdx.x * blockDim.x + threadIdx.x;
    int tot = 2 * P.M * P.K;
    if (i >= tot) return;
    int c = i / P.K, k = i - c * P.K;
    float v = (c < P.M) ? P.W1[(size_t)k * P.M + c] : P.W2[(size_t)k * P.M + (c - P.M)];
    P.Wt[i] = f2bf(v);
}

// ---------------- MFMA GEMM (round-11 config: 64x128 tile, LDS double-buffer) --------
// Swapped-operand MFMA: lane holds 1 row x 4 consecutive cols -> packed dword epilogue.
// cols<M -> V8 (fp8, row stride ldv), cols>=M -> R (bf16, row stride ldr)

struct GArg { const void* A; const ushort* Wt; uchar* V8; ushort* R; };
template<int NY> struct GArgs { GArg a[NY]; };

template<bool A_FP32, int NY>
__global__ __launch_bounds__(256) void gemm_mfma_k(GArgs<NY> P, int K, int M,
                                                   int ldv, int ldr, int n) {
    __shared__ __align__(16) uchar smem[30720];  // 2 x (As 5120 + Bs 10240); epi reuses
    const GArg& G = P.a[blockIdx.z];
    const void* __restrict__ Av = G.A;
    const ushort* __restrict__ Wt = G.Wt;

    int tid = threadIdx.x;
    int row0 = blockIdx.x * 64;
    int col0 = blockIdx.y * 128;
    int lane = tid & 63, wid = tid >> 6;
    int wm = wid & 1, wn = wid >> 1;
    int lrow = lane & 15, lko = (lane >> 4) * 8;

    f32x4 acc[2][4];
    #pragma unroll
    for (int i = 0; i < 2; ++i)
        #pragma unroll
        for (int j = 0; j < 4; ++j)
            acc[i][j] = (f32x4){0.f, 0.f, 0.f, 0.f};

    float4 fA0, fA1;
    uint4 uA, uB0, uB1;

    auto LOAD = [&](int it) {
        int kc = it << 5;
        if constexpr (A_FP32) {
            const float* A = (const float*)Av;
            int r = tid >> 3, s = tid & 7;
            int rg0 = row0 + r, rg1 = rg0 + 32;
            fA0 = (rg0 < n) ? *(const float4*)(A + (size_t)rg0 * K + kc + s * 4)
                            : make_float4(0.f, 0.f, 0.f, 0.f);
            fA1 = (rg1 < n) ? *(const float4*)(A + (size_t)rg1 * K + kc + s * 4)
                            : make_float4(0.f, 0.f, 0.f, 0.f);
        } else {
            const ushort* A = (const ushort*)Av;
            int r = tid >> 2, s = tid & 3;
            int rg = row0 + r;
            uA = (rg < n) ? *(const uint4*)(A + (size_t)rg * K + kc + s * 8)
                          : make_uint4(0u, 0u, 0u, 0u);
        }
        int rB = tid >> 2, sB = tid & 3;
        uB0 = *(const uint4*)(Wt + (size_t)(col0 + rB) * K + kc + sB * 8);
        uB1 = *(const uint4*)(Wt + (size_t)(col0 + rB + 64) * K + kc + sB * 8);
    };
    auto STORE_LDS = [&](int buf) {
        ushort* As = (ushort*)(smem + buf * 15360);
        ushort* Bs = As + 64 * 40;
        if constexpr (A_FP32) {
            int r = tid >> 3, s = tid & 7;
            *(uint2*)(&As[r * 40 + s * 4]) =
                make_uint2(pk2bf(fA0.x, fA0.y), pk2bf(fA0.z, fA0.w));
            *(uint2*)(&As[(r + 32) * 40 + s * 4]) =
                make_uint2(pk2bf(fA1.x, fA1.y), pk2bf(fA1.z, fA1.w));
        } else {
            int r = tid >> 2, s = tid & 3;
            *(uint4*)(&As[r * 40 + s * 8]) = uA;
        }
        int rB = tid >> 2, sB = tid & 3;
        *(uint4*)(&Bs[rB * 40 + sB * 8]) = uB0;
        *(uint4*)(&Bs[(rB + 64) * 40 + sB * 8]) = uB1;
    };

    const int nIt = K >> 5;
    LOAD(0);
    STORE_LDS(0);
    if (nIt > 1) LOAD(1);
    __syncthreads();

    for (int it = 0; it < nIt; ++it) {
        int cur = it & 1;
        if (it + 1 < nIt) STORE_LDS(cur ^ 1);
        if (it + 2 < nIt) LOAD(it + 2);
        {
            const ushort* As = (const ushort*)(smem + cur * 15360);
            const ushort* Bs = As + 64 * 40;
            bf16x8 af[2], bfr[4];
            #pragma unroll
            for (int i = 0; i < 2; ++i)
                af[i] = *(const bf16x8*)(&As[(wm * 32 + i * 16 + lrow) * 40 + lko]);
            #pragma unroll
            for (int j = 0; j < 4; ++j)
                bfr[j] = *(const bf16x8*)(&Bs[(wn * 64 + j * 16 + lrow) * 40 + lko]);
            #pragma unroll
            for (int i = 0; i < 2; ++i)
                #pragma unroll
                for (int j = 0; j < 4; ++j)
                    acc[i][j] = __builtin_amdgcn_mfma_f32_16x16x32_bf16(bfr[j], af[i], acc[i][j], 0, 0, 0);
        }
        __syncthreads();
    }

    // -------- packed-dword epilogue through LDS --------
    if (col0 + 128 <= M) {
        // pure fp8: C8dw[64][33]
        uint* C8 = (uint*)smem;
        #pragma unroll
        for (int i = 0; i < 2; ++i) {
            int m = wm * 32 + i * 16 + (lane & 15);
            #pragma unroll
            for (int j = 0; j < 4; ++j) {
                int dc = wn * 16 + j * 4 + (lane >> 4);
                C8[m * 33 + dc] = pk4f8(acc[i][j][0], acc[i][j][1], acc[i][j][2], acc[i][j][3]);
            }
        }
        __syncthreads();
        int row = tid >> 2, seg = tid & 3;
        if (row0 + row < n) {
            uint w[8];
            #pragma unroll
            for (int t = 0; t < 8; ++t) w[t] = C8[row * 33 + seg * 8 + t];
            uint4* g = (uint4*)(G.V8 + (size_t)(row0 + row) * ldv + col0 + seg * 32);
            g[0] = make_uint4(w[0], w[1], w[2], w[3]);
            g[1] = make_uint4(w[4], w[5], w[6], w[7]);
        }
    } else if (col0 >= M) {
        // pure bf16: C16dw[64][65]
        uint* C16 = (uint*)smem;
        #pragma unroll
        for (int i = 0; i < 2; ++i) {
            int m = wm * 32 + i * 16 + (lane & 15);
            #pragma unroll
            for (int j = 0; j < 4; ++j) {
                int dc = wn * 32 + j * 8 + (lane >> 4) * 2;
                C16[m * 65 + dc]     = pk2bf(acc[i][j][0], acc[i][j][1]);
                C16[m * 65 + dc + 1] = pk2bf(acc[i][j][2], acc[i][j][3]);
            }
        }
        __syncthreads();
        int row = tid >> 2, seg = tid & 3;
        if (row0 + row < n) {
            uint w[16];
            #pragma unroll
            for (int t = 0; t < 16; ++t) w[t] = C16[row * 65 + seg * 16 + t];
            uint4* g = (uint4*)(G.R + (size_t)(row0 + row) * ldr + (col0 - M) + seg * 32);
            g[0] = make_uint4(w[0], w[1], w[2], w[3]);
            g[1] = make_uint4(w[4], w[5], w[6], w[7]);
            g[2] = make_uint4(w[8], w[9], w[10], w[11]);
            g[3] = make_uint4(w[12], w[13], w[14], w[15]);
        }
    } else {
        // mixed (M == 64): wn=0 -> fp8 C8dw[64][17]; wn=1 -> bf16 C16dw[64][33]
        uint* C8  = (uint*)smem;
        uint* C16 = (uint*)(smem + 4608);
        #pragma unroll
        for (int i = 0; i < 2; ++i) {
            int m = wm * 32 + i * 16 + (lane & 15);
            #pragma unroll
            for (int j = 0; j < 4; ++j) {
                if (wn == 0) {
                    int dc = j * 4 + (lane >> 4);
                    C8[m * 17 + dc] = pk4f8(acc[i][j][0], acc[i][j][1], acc[i][j][2], acc[i][j][3]);
                } else {
                    int dc = j * 8 + (lane >> 4) * 2;
                    C16[m * 33 + dc]     = pk2bf(acc[i][j][0], acc[i][j][1]);
                    C16[m * 33 + dc + 1] = pk2bf(acc[i][j][2], acc[i][j][3]);
                }
            }
        }
        __syncthreads();
        int row = tid >> 2, seg = tid & 3;
        if (row0 + row < n) {
            uint w[4];
            #pragma unroll
            for (int t = 0; t < 4; ++t) w[t] = C8[row * 17 + seg * 4 + t];
            *(uint4*)(G.V8 + (size_t)(row0 + row) * ldv + seg * 16) =
                make_uint4(w[0], w[1], w[2], w[3]);
            uint v[8];
            #pragma unroll
            for (int t = 0; t < 8; ++t) v[t] = C16[row * 33 + seg * 8 + t];
            uint4* g = (uint4*)(G.R + (size_t)(row0 + row) * ldr + seg * 16);
            g[0] = make_uint4(v[0], v[1], v[2], v[3]);
            g[1] = make_uint4(v[4], v[5], v[6], v[7]);
        }
    }
}

// ---------------- fused agg, 512B interleaved rows (input: NZ=4, mid: NZ=2) ----------
// One wave per dst; 64 lanes x uint2 = one full 512B interleaved row per edge.
// U-deep unroll (U=8) -> 8 gather rows in flight per wave.

struct Bias4 { const float* b[4]; };

template<int NZ, int U>
__global__ __launch_bounds__(256) void agg_f512_k(const uchar* __restrict__ V8,
                                                  const ushort* __restrict__ R,
                                                  Bias4 B,
                                                  const float* __restrict__ inv_deg,
                                                  const int* __restrict__ row_start,
                                                  const int* __restrict__ csr_src,
                                                  ushort* __restrict__ xkout,
                                                  size_t tstride, int n) {
    constexpr int LPZ = 64 / NZ;
    int wid  = (blockIdx.x * blockDim.x + threadIdx.x) >> 6;
    int lane = threadIdx.x & 63;
    if (wid >= n) return;
    int dst = wid;
    int c0 = (lane & (LPZ - 1)) * 8;
    const float* bp = B.b[lane / LPZ] + c0;
    int off8 = lane * 8;

    float acc[8];
    #pragma unroll
    for (int q = 0; q < 8; ++q) acc[q] = 0.f;

    int s = row_start[dst], e = row_start[dst + 1];
    for (int g = s; g < e; g += U) {
        int idx[U];
        #pragma unroll
        for (int u = 0; u < U; ++u)
            idx[u] = (g + u < e) ? csr_src[g + u] : -1;
        uint2 d[U];
        #pragma unroll
        for (int u = 0; u < U; ++u) {
            d[u] = make_uint2(0u, 0u);
            if (idx[u] >= 0) d[u] = *(const uint2*)(V8 + (size_t)idx[u] * 512 + off8);
        }
        #pragma unroll
        for (int u = 0; u < U; ++u) {
            acc_fp8x4(acc,     d[u].x);
            acc_fp8x4(acc + 4, d[u].y);
        }
    }

    float inv = inv_deg[dst];
    float r[8];
    uint4 rr = *(const uint4*)(R + (size_t)dst * 512 + off8);
    uint rw[4] = {rr.x, rr.y, rr.z, rr.w};
    #pragma unroll
    for (int q = 0; q < 8; ++q) r[q] = acc[q] * inv + bp[q];
    #pragma unroll
    for (int p = 0; p < 4; ++p) {
        r[p * 2 + 0] += bf2f((ushort)(rw[p] & 0xFFFF));
        r[p * 2 + 1] += bf2f((ushort)(rw[p] >> 16));
    }
    #pragma unroll
    for (int q = 0; q < 8; ++q) r[q] = fmaxf(r[q], 0.f);   // relu

    uint4 o;
    o.x = pk2bf(r[0], r[1]); o.y = pk2bf(r[2], r[3]);
    o.z = pk2bf(r[4], r[5]); o.w = pk2bf(r[6], r[7]);
    *(uint4*)(xkout + (size_t)(lane >> 5) * tstride + (size_t)dst * 256 + (lane & 31) * 8) = o;
}

// ---------------- fused agg, 128B interleaved rows (out layer + head agg) ------------

template<int ACT, bool WF8, int U>
__global__ __launch_bounds__(256) void agg_f128_k(const uchar* __restrict__ V8,
                                                  const ushort* __restrict__ R,
                                                  const float* __restrict__ bias,
                                                  const float* __restrict__ inv_deg,
                                                  const int* __restrict__ row_start,
                                                  const int* __restrict__ csr_src,
                                                  ushort* __restrict__ outb, size_t tstride,
                                                  uchar* __restrict__ out8,
                                                  int n) {
    int wid  = (blockIdx.x * blockDim.x + threadIdx.x) >> 6;
    int lane = threadIdx.x & 63;
    if (wid >= n) return;
    int dst   = wid;
    int sub   = lane & 15;
    int eslot = lane >> 4;
    int task  = sub >> 3;
    int c0    = (sub & 7) * 8;

    float acc[8];
    #pragma unroll
    for (int q = 0; q < 8; ++q) acc[q] = 0.f;

    int s = row_start[dst], e = row_start[dst + 1];
    for (int g = s; g < e; g += 4 * U) {
        int idx[U];
        #pragma unroll
        for (int u = 0; u < U; ++u) {
            int t = g + u * 4 + eslot;
            idx[u] = (t < e) ? csr_src[t] : -1;
        }
        uint2 d[U];
        #pragma unroll
        for (int u = 0; u < U; ++u) {
            d[u] = make_uint2(0u, 0u);
            if (idx[u] >= 0) d[u] = *(const uint2*)(V8 + (size_t)idx[u] * 128 + sub * 8);
        }
        #pragma unroll
        for (int u = 0; u < U; ++u) {
            acc_fp8x4(acc,     d[u].x);
            acc_fp8x4(acc + 4, d[u].y);
        }
    }

    #pragma unroll
    for (int mask = 16; mask < 64; mask <<= 1)
        #pragma unroll
        for (int q = 0; q < 8; ++q)
            acc[q] += __shfl_xor(acc[q], mask);

    if (eslot == 0) {
        float inv = inv_deg[dst];
        float r[8];
        #pragma unroll
        for (int q = 0; q < 8; ++q) r[q] = acc[q] * inv;
        if (bias) {
            #pragma unroll
            for (int q = 0; q < 8; ++q) r[q] += bias[c0 + q];
        }
        if (R) {
            uint4 rr = *(const uint4*)(R + (size_t)dst * 128 + sub * 8);
            uint rw[4] = {rr.x, rr.y, rr.z, rr.w};
            #pragma unroll
            for (int p = 0; p < 4; ++p) {
                r[p * 2 + 0] += bf2f((ushort)(rw[p] & 0xFFFF));
                r[p * 2 + 1] += bf2f((ushort)(rw[p] >> 16));
            }
        }
        #pragma unroll
        for (int q = 0; q < 8; ++q) {
            if constexpr (ACT == 2) r[q] = 1.f / (1.f + expf(-r[q]));
        }
        uint4 o;
        o.x = pk2bf(r[0], r[1]); o.y = pk2bf(r[2], r[3]);
        o.z = pk2bf(r[4], r[5]); o.w = pk2bf(r[6], r[7]);
        *(uint4*)(outb + (size_t)task * tstride + (size_t)dst * 64 + c0) = o;
        if constexpr (WF8) {
            uint2 o8;
            o8.x = pk4f8(r[0], r[1], r[2], r[3]);
            o8.y = pk4f8(r[4], r[5], r[6], r[7]);
            *(uint2*)(out8 + (size_t)dst * 128 + sub * 8) = o8;
        }
    }
}

// ---------------- heads + cross-entropy (spill-free, both tasks via blockIdx.y) ------

template<int C>
__device__ inline float ce_from_z(float* z, int label) {
    float m = -1e30f;
    #pragma unroll
    for (int c = 0; c < C; ++c) { z[c] = 1.f / (1.f + expf(-z[c])); m = fmaxf(m, z[c]); }
    float ssum = 0.f, zl = 0.f;
    #pragma unroll
    for (int c = 0; c < C; ++c) { ssum += expf(z[c] - m); if (c == label) zl = z[c]; }
    return (logf(ssum) + m) - zl;
}

__global__ __launch_bounds__(256) void head_ce_k(const ushort* __restrict__ Ah,
                                                 const ushort* __restrict__ hk,
                                                 const float* __restrict__ Wl1, const float* __restrict__ b1, const float* __restrict__ Wr1,
                                                 const float* __restrict__ Wl2, const float* __restrict__ b2, const float* __restrict__ Wr2,
                                                 const float* __restrict__ Wl3, const float* __restrict__ b3, const float* __restrict__ Wr3,
                                                 const int* __restrict__ yv,
                                                 float* __restrict__ loss_acc, int n) {
    int ty = blockIdx.y;
    int nidx = blockIdx.x * blockDim.x + threadIdx.x;
    Wl1 += ty * 64 * 12; b1 += ty * 12; Wr1 += ty * 64 * 12;
    Wl2 += ty * 64 * 8;  b2 += ty * 8;  Wr2 += ty * 64 * 8;
    Wl3 += ty * 64 * 5;  b3 += ty * 5;  Wr3 += ty * 64 * 5;
    float lsum = 0.f;
    if (nidx < n) {
        float z0[12], z1[8], z2[5];
        #pragma unroll
        for (int c = 0; c < 12; ++c) z0[c] = b1[c];
        #pragma unroll
        for (int c = 0; c < 8; ++c) z1[c] = b2[c];
        #pragma unroll
        for (int c = 0; c < 5; ++c) z2[c] = b3[c];

        const ushort* ap = Ah + ((size_t)ty * NN + nidx) * 64;
        const ushort* hp = hk + ((size_t)ty * NN + nidx) * 64;
        for (int d8 = 0; d8 < 64; d8 += 8) {
            uint4 ua = *(const uint4*)(ap + d8);
            uint4 uh = *(const uint4*)(hp + d8);
            uint aw[4] = {ua.x, ua.y, ua.z, ua.w};
            uint hw[4] = {uh.x, uh.y, uh.z, uh.w};
            #pragma unroll
            for (int p = 0; p < 4; ++p) {
                #pragma unroll
                for (int half = 0; half < 2; ++half) {
                    int d = d8 + p * 2 + half;
                    float av = bf2f((ushort)(half ? (aw[p] >> 16) : (aw[p] & 0xFFFF)));
                    float hv = bf2f((ushort)(half ? (hw[p] >> 16) : (hw[p] & 0xFFFF)));
                    #pragma unroll
                    for (int c = 0; c < 12; ++c)
                        z0[c] = fmaf(av, Wl1[d * 12 + c], fmaf(hv, Wr1[d * 12 + c], z0[c]));
                    #pragma unroll
                    for (int c = 0; c < 8; ++c)
                        z1[c] = fmaf(av, Wl2[d * 8 + c], fmaf(hv, Wr2[d * 8 + c], z1[c]));
                    #pragma unroll
                    for (int c = 0; c < 5; ++c)
                        z2[c] = fmaf(av, Wl3[d * 5 + c], fmaf(hv, Wr3[d * 5 + c], z2[c]));
                }
            }
        }
        const int* yp = yv + ((size_t)ty * NN + nidx) * 3;
        lsum  = ce_from_z<12>(z0, yp[0]);
        lsum += ce_from_z<8 >(z1, yp[1]);
        lsum += ce_from_z<5 >(z2, yp[2]);
    }
    for (int off = 32; off > 0; off >>= 1) lsum += __shfl_down(lsum, off);
    __shared__ float ssum[4];
    int wv = threadIdx.x >> 6, ln = threadIdx.x & 63;
    if (ln == 0) ssum[wv] = lsum;
    __syncthreads();
    if (threadIdx.x == 0) atomicAdd(loss_acc, ssum[0] + ssum[1] + ssum[2] + ssum[3]);
}

__global__ void finalize_k(const float* __restrict__ loss_acc, float* __restrict__ out, int n) {
    out[0] = loss_acc[0] * (1.0f / (float)n);
}

// ---------------- host ----------------

extern "C" void kernel_launch(void* const* d_in, const int* in_sizes, int n_in,
                              void* d_out, int out_size, void* d_ws, size_t ws_size,
                              hipStream_t stream) {
    const float* X    = (const float*)d_in[0];
    const int*   esrc = (const int*)d_in[1];
    const int*   edst = (const int*)d_in[2];
    const int*   y    = (const int*)d_in[3];
    const float* Wl_i[2] = {(const float*)d_in[4], (const float*)d_in[7]};
    const float* bl_i[2] = {(const float*)d_in[5], (const float*)d_in[8]};
    const float* Wr_i[2] = {(const float*)d_in[6], (const float*)d_in[9]};
    const float* Wl_m = (const float*)d_in[10], *bl_m = (const float*)d_in[11], *Wr_m = (const float*)d_in[12];
    const float* Wl_o = (const float*)d_in[13], *bl_o = (const float*)d_in[14], *Wr_o = (const float*)d_in[15];
    const float* Wl_t1 = (const float*)d_in[16], *bl_t1 = (const float*)d_in[17], *Wr_t1 = (const float*)d_in[18];
    const float* Wl_t2 = (const float*)d_in[19], *bl_t2 = (const float*)d_in[20], *Wr_t2 = (const float*)d_in[21];
    const float* Wl_t3 = (const float*)d_in[22], *bl_t3 = (const float*)d_in[23], *Wr_t3 = (const float*)d_in[24];

    const int N = NN, E = NE;
    char* p = (char*)d_ws;
    auto alloc = [&](size_t bytes) -> char* {
        char* r = p;
        p += (bytes + 255) & ~(size_t)255;
        return r;
    };
    int*    counts    = (int*)alloc((size_t)N * 4);
    int*    row_start = (int*)alloc((size_t)(N + 1) * 4);
    int*    cursor    = (int*)alloc((size_t)N * 4);
    int*    bsum      = (int*)alloc(64 * 4);
    int*    csr_src   = (int*)alloc((size_t)E * 4);
    float*  inv_deg   = (float*)alloc((size_t)N * 4);
    float*  loss_acc  = (float*)alloc(256);
    uchar*  V8i  = (uchar*)alloc((size_t)N * 512);            // [n][4*128] fp8
    ushort* Ri   = (ushort*)alloc((size_t)N * 512 * 2);       // [n][4*128] bf16
    uchar*  V8m  = (uchar*)alloc((size_t)N * 512);            // [n][2*256] fp8
    ushort* Rm   = (ushort*)alloc((size_t)N * 512 * 2);       // [n][2*256] bf16
    uchar*  V8o  = (uchar*)alloc((size_t)N * 128);            // [n][2*64] fp8
    ushort* Ro   = (ushort*)alloc((size_t)N * 128 * 2);       // [n][2*64] bf16
    ushort* xk   = (ushort*)alloc((size_t)2 * N * 256 * 2);   // [2][n][256] bf16
    ushort* hk   = (ushort*)alloc((size_t)2 * N * 64 * 2);    // [2][n][64] bf16
    uchar*  hk8  = (uchar*)alloc((size_t)N * 128);            // [n][2*64] fp8
    ushort* Ah   = (ushort*)alloc((size_t)2 * N * 64 * 2);    // [2][n][64] bf16
    ushort* Wt_i0 = (ushort*)alloc((size_t)256 * 128 * 2);
    ushort* Wt_i1 = (ushort*)alloc((size_t)256 * 128 * 2);
    ushort* Wt_m  = (ushort*)alloc((size_t)512 * 256 * 2);
    ushort* Wt_o  = (ushort*)alloc((size_t)128 * 256 * 2);

    hipMemsetAsync(counts, 0, (size_t)N * 4, stream);
    hipMemsetAsync(loss_acc, 0, 4, stream);
    count_edges_k<<<(E + 255) / 256, 256, 0, stream>>>(edst, counts, E);
    const int NB = (N + 1023) / 1024;
    scan1_k<<<NB, 1024, 0, stream>>>(counts, row_start, bsum, N);
    scan2_k<<<1, 64, 0, stream>>>(bsum, NB);
    scan3_k<<<(N + 255) / 256, 256, 0, stream>>>(counts, bsum, row_start, cursor, inv_deg, N, E);
    fill_csr_k<<<(E + 255) / 256, 256, 0, stream>>>(esrc, edst, cursor, csr_src, E);

    {
        PrepArg p0 = {Wl_i[0], Wr_i[0], Wt_i0, 128, 128};
        PrepArg p1 = {Wl_i[1], Wr_i[1], Wt_i1, 128, 128};
        PrepArg p2 = {Wl_m, Wr_m, Wt_m, 256, 256};
        PrepArg p3 = {Wl_o, Wr_o, Wt_o, 256, 64};
        prep_w4_k<<<dim3(512, 4), 256, 0, stream>>>(p0, p1, p2, p3);
    }

    const int RB = (N + 63) / 64;
    const int AGB = (N + 3) / 4;
    const ushort* Wt_i[2] = {Wt_i0, Wt_i1};
    const size_t TSX = (size_t)N * 256;
    const size_t TSH = (size_t)N * 64;

    // ---- stage A: input GEMMs, all 4 (k,ch), interleaved epilogue ----
    {
        GArgs<4> P;
        for (int z = 0; z < 4; ++z)
            P.a[z] = {X + (size_t)z * N * 128, Wt_i[z & 1], V8i + z * 128, Ri + z * 128};
        gemm_mfma_k<true, 4><<<dim3(RB, 2, 4), 256, 0, stream>>>(P, 128, 128, 512, 512, N);
    }
    // ---- stage B: fused input agg (U=8 deep) ----
    {
        Bias4 B = {{bl_i[0], bl_i[1], bl_i[0], bl_i[1]}};
        agg_f512_k<4, 8><<<AGB, 256, 0, stream>>>(V8i, Ri, B, inv_deg, row_start, csr_src,
                                                  xk, TSX, N);
    }
    // ---- stage C: mid GEMMs, both tasks ----
    {
        GArgs<2> P;
        for (int k = 0; k < 2; ++k)
            P.a[k] = {xk + (size_t)k * TSX, Wt_m, V8m + k * 256, Rm + k * 256};
        gemm_mfma_k<false, 2><<<dim3(RB, 4, 2), 256, 0, stream>>>(P, 256, 256, 512, 512, N);
    }
    // ---- stage D: fused mid agg (U=8 deep) ----
    {
        Bias4 B = {{bl_m, bl_m, nullptr, nullptr}};
        agg_f512_k<2, 8><<<AGB, 256, 0, stream>>>(V8m, Rm, B, inv_deg, row_start, csr_src,
                                                  xk, TSX, N);
    }
    // ---- stage E: out GEMMs ----
    {
        GArgs<2> P;
        for (int k = 0; k < 2; ++k)
            P.a[k] = {xk + (size_t)k * TSX, Wt_o, V8o + k * 64, Ro + k * 64};
        gemm_mfma_k<false, 2><<<dim3(RB, 1, 2), 256, 0, stream>>>(P, 256, 64, 128, 128, N);
    }
    // ---- stage F: fused out agg (sigmoid, U=4) -> hk, hk8 ----
    agg_f128_k<2, true, 4><<<AGB, 256, 0, stream>>>(V8o, Ro, bl_o, inv_deg, row_start, csr_src,
                                                    hk, TSH, hk8, N);
    // ---- stage G: fused head agg (mean of hk, U=4) -> Ah ----
    agg_f128_k<0, false, 4><<<AGB, 256, 0, stream>>>(hk8, nullptr, nullptr, inv_deg, row_start, csr_src,
                                                     Ah, TSH, nullptr, N);
    // ---- stage H: heads + CE, both tasks ----
    head_ce_k<<<dim3((N + 255) / 256, 2), 256, 0, stream>>>(Ah, hk,
        Wl_t1, bl_t1, Wr_t1, Wl_t2, bl_t2, Wr_t2, Wl_t3, bl_t3, Wr_t3,
        y, loss_acc, N);

    finalize_k<<<1, 1, 0, stream>>>(loss_acc, (float*)d_out, N);
}

// Round 14
// 465.273 us; speedup vs baseline: 1.2452x; 1.0532x over previous
//
#include <hip/hip_runtime.h>
#include <math.h>

#define NN 50000
#define NE 800000

typedef short bf16x8 __attribute__((ext_vector_type(8)));
typedef float f32x4 __attribute__((ext_vector_type(4)));
typedef float f32x2 __attribute__((ext_vector_type(2)));

__device__ inline ushort f2bf(float f) {
    union { float f; uint u; } v; v.f = f;
    uint r = v.u + 0x7FFFu + ((v.u >> 16) & 1u);
    return (ushort)(r >> 16);
}
__device__ inline float bf2f(ushort h) {
    union { uint u; float f; } v; v.u = ((uint)h) << 16;
    return v.f;
}
// fp8 e4m3fn software codecs (bit-exact OCP e4m3fn incl. denormals)
__device__ inline uchar f2fp8(float f) {
    float a = fminf(fabsf(f), 448.f);
    union { float f; uint u; } v; v.f = a * 7.52316384526264e-37f;  // *2^-120
    uint r = (v.u + 0x7FFFFu + ((v.u >> 20) & 1u)) >> 20;           // RNE to e4m3 magnitude
    if (r > 0x7Eu) r = 0x7Eu;
    union { float f; uint u; } s; s.f = f;
    return (uchar)(r | ((s.u >> 31) << 7));
}
__device__ inline float fp8dec(uint b) {
    union { uint u; float f; } t; t.u = (b & 0x7Fu) << 20;
    union { float f; uint u; } o; o.f = t.f * 1.3292279957849159e36f;  // *2^120
    o.u |= (b & 0x80u) << 24;
    return o.f;
}
__device__ inline void acc_fp8x4(float* acc, uint u) {
#if __has_builtin(__builtin_amdgcn_cvt_pk_f32_fp8)
    f32x2 lo = __builtin_amdgcn_cvt_pk_f32_fp8((int)u, false);
    f32x2 hi = __builtin_amdgcn_cvt_pk_f32_fp8((int)u, true);
    acc[0] += lo[0]; acc[1] += lo[1]; acc[2] += hi[0]; acc[3] += hi[1];
#else
    acc[0] += fp8dec(u & 0xFFu);
    acc[1] += fp8dec((u >> 8) & 0xFFu);
    acc[2] += fp8dec((u >> 16) & 0xFFu);
    acc[3] += fp8dec(u >> 24);
#endif
}
__device__ inline uint pk2bf(float a, float b) {
    return (uint)f2bf(a) | ((uint)f2bf(b) << 16);
}
__device__ inline uint pk4f8(float a, float b, float c, float d) {
    return (uint)f2fp8(a) | ((uint)f2fp8(b) << 8) | ((uint)f2fp8(c) << 16) | ((uint)f2fp8(d) << 24);
}

// ---------------- CSR build ----------------

__global__ void count_edges_k(const int* __restrict__ edst, int* __restrict__ counts, int e) {
    int i = blockIdx.x * blockDim.x + threadIdx.x;
    if (i < e) atomicAdd(&counts[edst[i]], 1);
}

__global__ __launch_bounds__(1024) void scan1_k(const int* __restrict__ counts,
                                                int* __restrict__ row_start,
                                                int* __restrict__ bsum, int n) {
    __shared__ int sd[1024];
    int i = blockIdx.x * 1024 + threadIdx.x;
    int v = (i < n) ? counts[i] : 0;
    sd[threadIdx.x] = v;
    __syncthreads();
    for (int off = 1; off < 1024; off <<= 1) {
        int t = (threadIdx.x >= off) ? sd[threadIdx.x - off] : 0;
        __syncthreads();
        sd[threadIdx.x] += t;
        __syncthreads();
    }
    if (i < n) row_start[i] = sd[threadIdx.x] - v;
    if (threadIdx.x == 1023) bsum[blockIdx.x] = sd[1023];
}

__global__ void scan2_k(int* __restrict__ bsum, int nb) {
    int lane = threadIdx.x;
    int v = (lane < nb) ? bsum[lane] : 0;
    int orig = v;
    for (int off = 1; off < 64; off <<= 1) {
        int t = __shfl_up(v, off);
        if (lane >= off) v += t;
    }
    if (lane < nb) bsum[lane] = v - orig;
}

__global__ void scan3_k(const int* __restrict__ counts, const int* __restrict__ bsum,
                        int* __restrict__ row_start, int* __restrict__ cursor,
                        float* __restrict__ inv_deg, int n, int e) {
    int i = blockIdx.x * blockDim.x + threadIdx.x;
    if (i < n) {
        int rs = row_start[i] + bsum[i >> 10];
        row_start[i] = rs;
        cursor[i] = rs;
        inv_deg[i] = 1.0f / fmaxf((float)counts[i], 1.0f);
        if (i == 0) row_start[n] = e;
    }
}

__global__ void fill_csr_k(const int* __restrict__ esrc, const int* __restrict__ edst,
                           int* __restrict__ cursor, int* __restrict__ csr_src, int e) {
    int i = blockIdx.x * blockDim.x + threadIdx.x;
    if (i < e) {
        int pos = atomicAdd(&cursor[edst[i]], 1);
        csr_src[pos] = esrc[i];
    }
}

// ---------------- weight prep (all 4 fused) ----------------

struct PrepArg { const float* W1; const float* W2; ushort* Wt; int K; int M; };

__global__ void prep_w4_k(PrepArg p0, PrepArg p1, PrepArg p2, PrepArg p3) {
    PrepArg P = (blockIdx.y == 0) ? p0 : (blockIdx.y == 1) ? p1 : (blockIdx.y == 2) ? p2 : p3;
    int i = blockIdx.x * blockDim.x + threadIdx.x;
    int tot = 2 * P.M * P.K;
    if (i >= tot) return;
    int c = i / P.K, k = i - c * P.K;
    float v = (c < P.M) ? P.W1[(size_t)k * P.M + c] : P.W2[(size_t)k * P.M + (c - P.M)];
    P.Wt[i] = f2bf(v);
}

// ---------------- MFMA GEMM: 64x128 tile, LDS dbuf, all-fp8 outputs ------------------
// Swapped-operand MFMA (lane = 1 row x 4 consecutive cols). 1D grid, col-block fastest
// (temporal L2/L3 locality for A re-reads). cols<M -> V8, cols>=M -> R8 (both fp8).

struct GArg { const void* A; const ushort* Wt; uchar* V8; uchar* R8; };
template<int NY> struct GArgs { GArg a[NY]; };

template<bool A_FP32, int NY>
__global__ __launch_bounds__(256) void gemm_mfma_k(GArgs<NY> P, int K, int M,
                                                   int ldv, int ldr, int n) {
    __shared__ __align__(16) uchar smem[30720];  // 2 x (As 5120 + Bs 10240); epi reuses
    const GArg& G = P.a[blockIdx.z];
    const void* __restrict__ Av = G.A;
    const ushort* __restrict__ Wt = G.Wt;

    int tid = threadIdx.x;
    int NC = (2 * M) >> 7; if (NC == 0) NC = 1;   // column blocks of 128
    int cb = blockIdx.x % NC;
    int rb = blockIdx.x / NC;
    int row0 = rb * 64;
    int col0 = cb * 128;
    int lane = tid & 63, wid = tid >> 6;
    int wm = wid & 1, wn = wid >> 1;
    int lrow = lane & 15, lko = (lane >> 4) * 8;

    f32x4 acc[2][4];
    #pragma unroll
    for (int i = 0; i < 2; ++i)
        #pragma unroll
        for (int j = 0; j < 4; ++j)
            acc[i][j] = (f32x4){0.f, 0.f, 0.f, 0.f};

    float4 fA0, fA1;
    uint4 uA, uB0, uB1;

    auto LOAD = [&](int it) {
        int kc = it << 5;
        if constexpr (A_FP32) {
            const float* A = (const float*)Av;
            int r = tid >> 3, s = tid & 7;
            int rg0 = row0 + r, rg1 = rg0 + 32;
            fA0 = (rg0 < n) ? *(const float4*)(A + (size_t)rg0 * K + kc + s * 4)
                            : make_float4(0.f, 0.f, 0.f, 0.f);
            fA1 = (rg1 < n) ? *(const float4*)(A + (size_t)rg1 * K + kc + s * 4)
                            : make_float4(0.f, 0.f, 0.f, 0.f);
        } else {
            const ushort* A = (const ushort*)Av;
            int r = tid >> 2, s = tid & 3;
            int rg = row0 + r;
            uA = (rg < n) ? *(const uint4*)(A + (size_t)rg * K + kc + s * 8)
                          : make_uint4(0u, 0u, 0u, 0u);
        }
        int rB = tid >> 2, sB = tid & 3;
        uB0 = *(const uint4*)(Wt + (size_t)(col0 + rB) * K + kc + sB * 8);
        uB1 = *(const uint4*)(Wt + (size_t)(col0 + rB + 64) * K + kc + sB * 8);
    };
    auto STORE_LDS = [&](int buf) {
        ushort* As = (ushort*)(smem + buf * 15360);
        ushort* Bs = As + 64 * 40;
        if constexpr (A_FP32) {
            int r = tid >> 3, s = tid & 7;
            *(uint2*)(&As[r * 40 + s * 4]) =
                make_uint2(pk2bf(fA0.x, fA0.y), pk2bf(fA0.z, fA0.w));
            *(uint2*)(&As[(r + 32) * 40 + s * 4]) =
                make_uint2(pk2bf(fA1.x, fA1.y), pk2bf(fA1.z, fA1.w));
        } else {
            int r = tid >> 2, s = tid & 3;
            *(uint4*)(&As[r * 40 + s * 8]) = uA;
        }
        int rB = tid >> 2, sB = tid & 3;
        *(uint4*)(&Bs[rB * 40 + sB * 8]) = uB0;
        *(uint4*)(&Bs[(rB + 64) * 40 + sB * 8]) = uB1;
    };

    const int nIt = K >> 5;
    LOAD(0);
    STORE_LDS(0);
    if (nIt > 1) LOAD(1);
    __syncthreads();

    for (int it = 0; it < nIt; ++it) {
        int cur = it & 1;
        if (it + 1 < nIt) STORE_LDS(cur ^ 1);
        if (it + 2 < nIt) LOAD(it + 2);
        {
            const ushort* As = (const ushort*)(smem + cur * 15360);
            const ushort* Bs = As + 64 * 40;
            bf16x8 af[2], bfr[4];
            #pragma unroll
            for (int i = 0; i < 2; ++i)
                af[i] = *(const bf16x8*)(&As[(wm * 32 + i * 16 + lrow) * 40 + lko]);
            #pragma unroll
            for (int j = 0; j < 4; ++j)
                bfr[j] = *(const bf16x8*)(&Bs[(wn * 64 + j * 16 + lrow) * 40 + lko]);
            #pragma unroll
            for (int i = 0; i < 2; ++i)
                #pragma unroll
                for (int j = 0; j < 4; ++j)
                    acc[i][j] = __builtin_amdgcn_mfma_f32_16x16x32_bf16(bfr[j], af[i], acc[i][j], 0, 0, 0);
        }
        __syncthreads();
    }

    // -------- unified fp8 packed-dword epilogue: C8dw[64][33] --------
    uint* C8 = (uint*)smem;
    #pragma unroll
    for (int i = 0; i < 2; ++i) {
        int m = wm * 32 + i * 16 + (lane & 15);
        #pragma unroll
        for (int j = 0; j < 4; ++j) {
            int dc = wn * 16 + j * 4 + (lane >> 4);
            C8[m * 33 + dc] = pk4f8(acc[i][j][0], acc[i][j][1], acc[i][j][2], acc[i][j][3]);
        }
    }
    __syncthreads();
    int row = tid >> 2, seg = tid & 3;   // 4 segs x 32B per 128B row
    if (row0 + row < n) {
        uint w[8];
        #pragma unroll
        for (int t = 0; t < 8; ++t) w[t] = C8[row * 33 + seg * 8 + t];
        uchar* base;
        if (M >= 128) {
            base = (col0 < M) ? G.V8 + (size_t)(row0 + row) * ldv + col0 + seg * 32
                              : G.R8 + (size_t)(row0 + row) * ldr + (col0 - M) + seg * 32;
        } else {
            // M == 64: seg 0,1 -> V8 (cols 0-63), seg 2,3 -> R8 (cols 0-63)
            base = (seg < 2) ? G.V8 + (size_t)(row0 + row) * ldv + seg * 32
                             : G.R8 + (size_t)(row0 + row) * ldr + (seg - 2) * 32;
        }
        ((uint4*)base)[0] = make_uint4(w[0], w[1], w[2], w[3]);
        ((uint4*)base)[1] = make_uint4(w[4], w[5], w[6], w[7]);
    }
}

// ---------------- fused agg, 512B interleaved rows (input: NZ=4, mid: NZ=2) ----------
// One wave per dst; 64 lanes x uint2 = one full 512B interleaved row per edge.
// U-deep unroll -> U gather rows in flight per wave. R is fp8 (512B rows).

struct Bias4 { const float* b[4]; };

template<int NZ, int U>
__global__ __launch_bounds__(256) void agg_f512_k(const uchar* __restrict__ V8,
                                                  const uchar* __restrict__ R8,
                                                  Bias4 B,
                                                  const float* __restrict__ inv_deg,
                                                  const int* __restrict__ row_start,
                                                  const int* __restrict__ csr_src,
                                                  ushort* __restrict__ xkout,
                                                  size_t tstride, int n) {
    constexpr int LPZ = 64 / NZ;
    int wid  = (blockIdx.x * blockDim.x + threadIdx.x) >> 6;
    int lane = threadIdx.x & 63;
    if (wid >= n) return;
    int dst = wid;
    int c0 = (lane & (LPZ - 1)) * 8;
    const float* bp = B.b[lane / LPZ] + c0;
    int off8 = lane * 8;

    float acc[8];
    #pragma unroll
    for (int q = 0; q < 8; ++q) acc[q] = 0.f;

    int s = row_start[dst], e = row_start[dst + 1];
    for (int g = s; g < e; g += U) {
        int idx[U];
        #pragma unroll
        for (int u = 0; u < U; ++u)
            idx[u] = (g + u < e) ? csr_src[g + u] : -1;
        uint2 d[U];
        #pragma unroll
        for (int u = 0; u < U; ++u) {
            d[u] = make_uint2(0u, 0u);
            if (idx[u] >= 0) d[u] = *(const uint2*)(V8 + (size_t)idx[u] * 512 + off8);
        }
        #pragma unroll
        for (int u = 0; u < U; ++u) {
            acc_fp8x4(acc,     d[u].x);
            acc_fp8x4(acc + 4, d[u].y);
        }
    }

    float inv = inv_deg[dst];
    float r[8];
    #pragma unroll
    for (int q = 0; q < 8; ++q) r[q] = acc[q] * inv + bp[q];
    uint2 rr = *(const uint2*)(R8 + (size_t)dst * 512 + off8);
    acc_fp8x4(r,     rr.x);
    acc_fp8x4(r + 4, rr.y);
    #pragma unroll
    for (int q = 0; q < 8; ++q) r[q] = fmaxf(r[q], 0.f);   // relu

    uint4 o;
    o.x = pk2bf(r[0], r[1]); o.y = pk2bf(r[2], r[3]);
    o.z = pk2bf(r[4], r[5]); o.w = pk2bf(r[6], r[7]);
    *(uint4*)(xkout + (size_t)(lane >> 5) * tstride + (size_t)dst * 256 + (lane & 31) * 8) = o;
}

// ---------------- fused agg, 128B interleaved rows (out layer + head agg) ------------
// R is fp8 (128B rows).

template<int ACT, bool WF8, int U>
__global__ __launch_bounds__(256) void agg_f128_k(const uchar* __restrict__ V8,
                                                  const uchar* __restrict__ R8,
                                                  const float* __restrict__ bias,
                                                  const float* __restrict__ inv_deg,
                                                  const int* __restrict__ row_start,
                                                  const int* __restrict__ csr_src,
                                                  ushort* __restrict__ outb, size_t tstride,
                                                  uchar* __restrict__ out8,
                                                  int n) {
    int wid  = (blockIdx.x * blockDim.x + threadIdx.x) >> 6;
    int lane = threadIdx.x & 63;
    if (wid >= n) return;
    int dst   = wid;
    int sub   = lane & 15;
    int eslot = lane >> 4;
    int task  = sub >> 3;
    int c0    = (sub & 7) * 8;

    float acc[8];
    #pragma unroll
    for (int q = 0; q < 8; ++q) acc[q] = 0.f;

    int s = row_start[dst], e = row_start[dst + 1];
    for (int g = s; g < e; g += 4 * U) {
        int idx[U];
        #pragma unroll
        for (int u = 0; u < U; ++u) {
            int t = g + u * 4 + eslot;
            idx[u] = (t < e) ? csr_src[t] : -1;
        }
        uint2 d[U];
        #pragma unroll
        for (int u = 0; u < U; ++u) {
            d[u] = make_uint2(0u, 0u);
            if (idx[u] >= 0) d[u] = *(const uint2*)(V8 + (size_t)idx[u] * 128 + sub * 8);
        }
        #pragma unroll
        for (int u = 0; u < U; ++u) {
            acc_fp8x4(acc,     d[u].x);
            acc_fp8x4(acc + 4, d[u].y);
        }
    }

    #pragma unroll
    for (int mask = 16; mask < 64; mask <<= 1)
        #pragma unroll
        for (int q = 0; q < 8; ++q)
            acc[q] += __shfl_xor(acc[q], mask);

    if (eslot == 0) {
        float inv = inv_deg[dst];
        float r[8];
        #pragma unroll
        for (int q = 0; q < 8; ++q) r[q] = acc[q] * inv;
        if (bias) {
            #pragma unroll
            for (int q = 0; q < 8; ++q) r[q] += bias[c0 + q];
        }
        if (R8) {
            uint2 rr = *(const uint2*)(R8 + (size_t)dst * 128 + sub * 8);
            acc_fp8x4(r,     rr.x);
            acc_fp8x4(r + 4, rr.y);
        }
        #pragma unroll
        for (int q = 0; q < 8; ++q) {
            if constexpr (ACT == 2) r[q] = 1.f / (1.f + expf(-r[q]));
        }
        uint4 o;
        o.x = pk2bf(r[0], r[1]); o.y = pk2bf(r[2], r[3]);
        o.z = pk2bf(r[4], r[5]); o.w = pk2bf(r[6], r[7]);
        *(uint4*)(outb + (size_t)task * tstride + (size_t)dst * 64 + c0) = o;
        if constexpr (WF8) {
            uint2 o8;
            o8.x = pk4f8(r[0], r[1], r[2], r[3]);
            o8.y = pk4f8(r[4], r[5], r[6], r[7]);
            *(uint2*)(out8 + (size_t)dst * 128 + sub * 8) = o8;
        }
    }
}

// ---------------- heads + cross-entropy (spill-free, both tasks via blockIdx.y) ------

template<int C>
__device__ inline float ce_from_z(float* z, int label) {
    float m = -1e30f;
    #pragma unroll
    for (int c = 0; c < C; ++c) { z[c] = 1.f / (1.f + expf(-z[c])); m = fmaxf(m, z[c]); }
    float ssum = 0.f, zl = 0.f;
    #pragma unroll
    for (int c = 0; c < C; ++c) { ssum += expf(z[c] - m); if (c == label) zl = z[c]; }
    return (logf(ssum) + m) - zl;
}

__global__ __launch_bounds__(256) void head_ce_k(const ushort* __restrict__ Ah,
                                                 const ushort* __restrict__ hk,
                                                 const float* __restrict__ Wl1, const float* __restrict__ b1, const float* __restrict__ Wr1,
                                                 const float* __restrict__ Wl2, const float* __restrict__ b2, const float* __restrict__ Wr2,
                                                 const float* __restrict__ Wl3, const float* __restrict__ b3, const float* __restrict__ Wr3,
                                                 const int* __restrict__ yv,
                                                 float* __restrict__ loss_acc, int n) {
    int ty = blockIdx.y;
    int nidx = blockIdx.x * blockDim.x + threadIdx.x;
    Wl1 += ty * 64 * 12; b1 += ty * 12; Wr1 += ty * 64 * 12;
    Wl2 += ty * 64 * 8;  b2 += ty * 8;  Wr2 += ty * 64 * 8;
    Wl3 += ty * 64 * 5;  b3 += ty * 5;  Wr3 += ty * 64 * 5;
    float lsum = 0.f;
    if (nidx < n) {
        float z0[12], z1[8], z2[5];
        #pragma unroll
        for (int c = 0; c < 12; ++c) z0[c] = b1[c];
        #pragma unroll
        for (int c = 0; c < 8; ++c) z1[c] = b2[c];
        #pragma unroll
        for (int c = 0; c < 5; ++c) z2[c] = b3[c];

        const ushort* ap = Ah + ((size_t)ty * NN + nidx) * 64;
        const ushort* hp = hk + ((size_t)ty * NN + nidx) * 64;
        for (int d8 = 0; d8 < 64; d8 += 8) {
            uint4 ua = *(const uint4*)(ap + d8);
            uint4 uh = *(const uint4*)(hp + d8);
            uint aw[4] = {ua.x, ua.y, ua.z, ua.w};
            uint hw[4] = {uh.x, uh.y, uh.z, uh.w};
            #pragma unroll
            for (int p = 0; p < 4; ++p) {
                #pragma unroll
                for (int half = 0; half < 2; ++half) {
                    int d = d8 + p * 2 + half;
                    float av = bf2f((ushort)(half ? (aw[p] >> 16) : (aw[p] & 0xFFFF)));
                    float hv = bf2f((ushort)(half ? (hw[p] >> 16) : (hw[p] & 0xFFFF)));
                    #pragma unroll
                    for (int c = 0; c < 12; ++c)
                        z0[c] = fmaf(av, Wl1[d * 12 + c], fmaf(hv, Wr1[d * 12 + c], z0[c]));
                    #pragma unroll
                    for (int c = 0; c < 8; ++c)
                        z1[c] = fmaf(av, Wl2[d * 8 + c], fmaf(hv, Wr2[d * 8 + c], z1[c]));
                    #pragma unroll
                    for (int c = 0; c < 5; ++c)
                        z2[c] = fmaf(av, Wl3[d * 5 + c], fmaf(hv, Wr3[d * 5 + c], z2[c]));
                }
            }
        }
        const int* yp = yv + ((size_t)ty * NN + nidx) * 3;
        lsum  = ce_from_z<12>(z0, yp[0]);
        lsum += ce_from_z<8 >(z1, yp[1]);
        lsum += ce_from_z<5 >(z2, yp[2]);
    }
    for (int off = 32; off > 0; off >>= 1) lsum += __shfl_down(lsum, off);
    __shared__ float ssum[4];
    int wv = threadIdx.x >> 6, ln = threadIdx.x & 63;
    if (ln == 0) ssum[wv] = lsum;
    __syncthreads();
    if (threadIdx.x == 0) atomicAdd(loss_acc, ssum[0] + ssum[1] + ssum[2] + ssum[3]);
}

__global__ void finalize_k(const float* __restrict__ loss_acc, float* __restrict__ out, int n) {
    out[0] = loss_acc[0] * (1.0f / (float)n);
}

// ---------------- host ----------------

extern "C" void kernel_launch(void* const* d_in, const int* in_sizes, int n_in,
                              void* d_out, int out_size, void* d_ws, size_t ws_size,
                              hipStream_t stream) {
    const float* X    = (const float*)d_in[0];
    const int*   esrc = (const int*)d_in[1];
    const int*   edst = (const int*)d_in[2];
    const int*   y    = (const int*)d_in[3];
    const float* Wl_i[2] = {(const float*)d_in[4], (const float*)d_in[7]};
    const float* bl_i[2] = {(const float*)d_in[5], (const float*)d_in[8]};
    const float* Wr_i[2] = {(const float*)d_in[6], (const float*)d_in[9]};
    const float* Wl_m = (const float*)d_in[10], *bl_m = (const float*)d_in[11], *Wr_m = (const float*)d_in[12];
    const float* Wl_o = (const float*)d_in[13], *bl_o = (const float*)d_in[14], *Wr_o = (const float*)d_in[15];
    const float* Wl_t1 = (const float*)d_in[16], *bl_t1 = (const float*)d_in[17], *Wr_t1 = (const float*)d_in[18];
    const float* Wl_t2 = (const float*)d_in[19], *bl_t2 = (const float*)d_in[20], *Wr_t2 = (const float*)d_in[21];
    const float* Wl_t3 = (const float*)d_in[22], *bl_t3 = (const float*)d_in[23], *Wr_t3 = (const float*)d_in[24];

    const int N = NN, E = NE;
    char* p = (char*)d_ws;
    auto alloc = [&](size_t bytes) -> char* {
        char* r = p;
        p += (bytes + 255) & ~(size_t)255;
        return r;
    };
    int*    counts    = (int*)alloc((size_t)N * 4);
    int*    row_start = (int*)alloc((size_t)(N + 1) * 4);
    int*    cursor    = (int*)alloc((size_t)N * 4);
    int*    bsum      = (int*)alloc(64 * 4);
    int*    csr_src   = (int*)alloc((size_t)E * 4);
    float*  inv_deg   = (float*)alloc((size_t)N * 4);
    float*  loss_acc  = (float*)alloc(256);
    uchar*  V8i  = (uchar*)alloc((size_t)N * 512);            // [n][4*128] fp8
    uchar*  Ri8  = (uchar*)alloc((size_t)N * 512);            // [n][4*128] fp8
    uchar*  V8m  = (uchar*)alloc((size_t)N * 512);            // [n][2*256] fp8
    uchar*  Rm8  = (uchar*)alloc((size_t)N * 512);            // [n][2*256] fp8
    uchar*  V8o  = (uchar*)alloc((size_t)N * 128);            // [n][2*64] fp8
    uchar*  Ro8  = (uchar*)alloc((size_t)N * 128);            // [n][2*64] fp8
    ushort* xk   = (ushort*)alloc((size_t)2 * N * 256 * 2);   // [2][n][256] bf16
    ushort* hk   = (ushort*)alloc((size_t)2 * N * 64 * 2);    // [2][n][64] bf16
    uchar*  hk8  = (uchar*)alloc((size_t)N * 128);            // [n][2*64] fp8
    ushort* Ah   = (ushort*)alloc((size_t)2 * N * 64 * 2);    // [2][n][64] bf16
    ushort* Wt_i0 = (ushort*)alloc((size_t)256 * 128 * 2);
    ushort* Wt_i1 = (ushort*)alloc((size_t)256 * 128 * 2);
    ushort* Wt_m  = (ushort*)alloc((size_t)512 * 256 * 2);
    ushort* Wt_o  = (ushort*)alloc((size_t)128 * 256 * 2);

    hipMemsetAsync(counts, 0, (size_t)N * 4, stream);
    hipMemsetAsync(loss_acc, 0, 4, stream);
    count_edges_k<<<(E + 255) / 256, 256, 0, stream>>>(edst, counts, E);
    const int NB = (N + 1023) / 1024;
    scan1_k<<<NB, 1024, 0, stream>>>(counts, row_start, bsum, N);
    scan2_k<<<1, 64, 0, stream>>>(bsum, NB);
    scan3_k<<<(N + 255) / 256, 256, 0, stream>>>(counts, bsum, row_start, cursor, inv_deg, N, E);
    fill_csr_k<<<(E + 255) / 256, 256, 0, stream>>>(esrc, edst, cursor, csr_src, E);

    {
        PrepArg p0 = {Wl_i[0], Wr_i[0], Wt_i0, 128, 128};
        PrepArg p1 = {Wl_i[1], Wr_i[1], Wt_i1, 128, 128};
        PrepArg p2 = {Wl_m, Wr_m, Wt_m, 256, 256};
        PrepArg p3 = {Wl_o, Wr_o, Wt_o, 256, 64};
        prep_w4_k<<<dim3(512, 4), 256, 0, stream>>>(p0, p1, p2, p3);
    }

    const int RB = (N + 63) / 64;
    const int AGB = (N + 3) / 4;
    const ushort* Wt_i[2] = {Wt_i0, Wt_i1};
    const size_t TSX = (size_t)N * 256;
    const size_t TSH = (size_t)N * 64;

    // ---- stage A: input GEMMs, all 4 (k,ch) — 1D grid, col-block fastest ----
    {
        GArgs<4> P;
        for (int z = 0; z < 4; ++z)
            P.a[z] = {X + (size_t)z * N * 128, Wt_i[z & 1], V8i + z * 128, Ri8 + z * 128};
        gemm_mfma_k<true, 4><<<dim3(RB * 2, 1, 4), 256, 0, stream>>>(P, 128, 128, 512, 512, N);
    }
    // ---- stage B: fused input agg (U=8) ----
    {
        Bias4 B = {{bl_i[0], bl_i[1], bl_i[0], bl_i[1]}};
        agg_f512_k<4, 8><<<AGB, 256, 0, stream>>>(V8i, Ri8, B, inv_deg, row_start, csr_src,
                                                  xk, TSX, N);
    }
    // ---- stage C: mid GEMMs, both tasks ----
    {
        GArgs<2> P;
        for (int k = 0; k < 2; ++k)
            P.a[k] = {xk + (size_t)k * TSX, Wt_m, V8m + k * 256, Rm8 + k * 256};
        gemm_mfma_k<false, 2><<<dim3(RB * 4, 1, 2), 256, 0, stream>>>(P, 256, 256, 512, 512, N);
    }
    // ---- stage D: fused mid agg (U=8) ----
    {
        Bias4 B = {{bl_m, bl_m, nullptr, nullptr}};
        agg_f512_k<2, 8><<<AGB, 256, 0, stream>>>(V8m, Rm8, B, inv_deg, row_start, csr_src,
                                                  xk, TSX, N);
    }
    // ---- stage E: out GEMMs ----
    {
        GArgs<2> P;
        for (int k = 0; k < 2; ++k)
            P.a[k] = {xk + (size_t)k * TSX, Wt_o, V8o + k * 64, Ro8 + k * 64};
        gemm_mfma_k<false, 2><<<dim3(RB, 1, 2), 256, 0, stream>>>(P, 256, 64, 128, 128, N);
    }
    // ---- stage F: fused out agg (sigmoid, U=4) -> hk, hk8 ----
    agg_f128_k<2, true, 4><<<AGB, 256, 0, stream>>>(V8o, Ro8, bl_o, inv_deg, row_start, csr_src,
                                                    hk, TSH, hk8, N);
    // ---- stage G: fused head agg (mean of hk, U=4) -> Ah ----
    agg_f128_k<0, false, 4><<<AGB, 256, 0, stream>>>(hk8, nullptr, nullptr, inv_deg, row_start, csr_src,
                                                     Ah, TSH, nullptr, N);
    // ---- stage H: heads + CE, both tasks ----
    head_ce_k<<<dim3((N + 255) / 256, 2), 256, 0, stream>>>(Ah, hk,
        Wl_t1, bl_t1, Wr_t1, Wl_t2, bl_t2, Wr_t2, Wl_t3, bl_t3, Wr_t3,
        y, loss_acc, N);

    finalize_k<<<1, 1, 0, stream>>>(loss_acc, (float*)d_out, N);
}

// Round 15
// 449.658 us; speedup vs baseline: 1.2885x; 1.0347x over previous
//
#include <hip/hip_runtime.h>
#include <math.h>

#define NN 50000
#define NE 800000

typedef short bf16x8 __attribute__((ext_vector_type(8)));
typedef float f32x4 __attribute__((ext_vector_type(4)));
typedef float f32x2 __attribute__((ext_vector_type(2)));

__device__ inline ushort f2bf(float f) {
    union { float f; uint u; } v; v.f = f;
    uint r = v.u + 0x7FFFu + ((v.u >> 16) & 1u);
    return (ushort)(r >> 16);
}
__device__ inline float bf2f(ushort h) {
    union { uint u; float f; } v; v.u = ((uint)h) << 16;
    return v.f;
}
// fp8 e4m3fn codecs: HW packed convert when available, software fallback
__device__ inline uchar f2fp8_sw(float f) {
    float a = fminf(fabsf(f), 448.f);
    union { float f; uint u; } v; v.f = a * 7.52316384526264e-37f;  // *2^-120
    uint r = (v.u + 0x7FFFFu + ((v.u >> 20) & 1u)) >> 20;
    if (r > 0x7Eu) r = 0x7Eu;
    union { float f; uint u; } s; s.f = f;
    return (uchar)(r | ((s.u >> 31) << 7));
}
__device__ inline uint pk4f8(float a, float b, float c, float d) {
#if __has_builtin(__builtin_amdgcn_cvt_pk_fp8_f32)
    int v = __builtin_amdgcn_cvt_pk_fp8_f32(a, b, 0, false);
    v = __builtin_amdgcn_cvt_pk_fp8_f32(c, d, v, true);
    return (uint)v;
#else
    return (uint)f2fp8_sw(a) | ((uint)f2fp8_sw(b) << 8) |
           ((uint)f2fp8_sw(c) << 16) | ((uint)f2fp8_sw(d) << 24);
#endif
}
__device__ inline float fp8dec(uint b) {
    union { uint u; float f; } t; t.u = (b & 0x7Fu) << 20;
    union { float f; uint u; } o; o.f = t.f * 1.3292279957849159e36f;  // *2^120
    o.u |= (b & 0x80u) << 24;
    return o.f;
}
__device__ inline void acc_fp8x4(float* acc, uint u) {
#if __has_builtin(__builtin_amdgcn_cvt_pk_f32_fp8)
    f32x2 lo = __builtin_amdgcn_cvt_pk_f32_fp8((int)u, false);
    f32x2 hi = __builtin_amdgcn_cvt_pk_f32_fp8((int)u, true);
    acc[0] += lo[0]; acc[1] += lo[1]; acc[2] += hi[0]; acc[3] += hi[1];
#else
    acc[0] += fp8dec(u & 0xFFu);
    acc[1] += fp8dec((u >> 8) & 0xFFu);
    acc[2] += fp8dec((u >> 16) & 0xFFu);
    acc[3] += fp8dec(u >> 24);
#endif
}
__device__ inline uint pk2bf(float a, float b) {
    return (uint)f2bf(a) | ((uint)f2bf(b) << 16);
}

// ---------------- CSR build ----------------

__global__ void count_edges_k(const int* __restrict__ edst, int* __restrict__ counts, int e) {
    int i = blockIdx.x * blockDim.x + threadIdx.x;
    if (i < e) atomicAdd(&counts[edst[i]], 1);
}

__global__ __launch_bounds__(1024) void scan1_k(const int* __restrict__ counts,
                                                int* __restrict__ row_start,
                                                int* __restrict__ bsum, int n) {
    __shared__ int sd[1024];
    int i = blockIdx.x * 1024 + threadIdx.x;
    int v = (i < n) ? counts[i] : 0;
    sd[threadIdx.x] = v;
    __syncthreads();
    for (int off = 1; off < 1024; off <<= 1) {
        int t = (threadIdx.x >= off) ? sd[threadIdx.x - off] : 0;
        __syncthreads();
        sd[threadIdx.x] += t;
        __syncthreads();
    }
    if (i < n) row_start[i] = sd[threadIdx.x] - v;
    if (threadIdx.x == 1023) bsum[blockIdx.x] = sd[1023];
}

__global__ void scan2_k(int* __restrict__ bsum, int nb) {
    int lane = threadIdx.x;
    int v = (lane < nb) ? bsum[lane] : 0;
    int orig = v;
    for (int off = 1; off < 64; off <<= 1) {
        int t = __shfl_up(v, off);
        if (lane >= off) v += t;
    }
    if (lane < nb) bsum[lane] = v - orig;
}

__global__ void scan3_k(const int* __restrict__ counts, const int* __restrict__ bsum,
                        int* __restrict__ row_start, int* __restrict__ cursor,
                        float* __restrict__ inv_deg, int n, int e) {
    int i = blockIdx.x * blockDim.x + threadIdx.x;
    if (i < n) {
        int rs = row_start[i] + bsum[i >> 10];
        row_start[i] = rs;
        cursor[i] = rs;
        inv_deg[i] = 1.0f / fmaxf((float)counts[i], 1.0f);
        if (i == 0) row_start[n] = e;
    }
}

__global__ void fill_csr_k(const int* __restrict__ esrc, const int* __restrict__ edst,
                           int* __restrict__ cursor, int* __restrict__ csr_src, int e) {
    int i = blockIdx.x * blockDim.x + threadIdx.x;
    if (i < e) {
        int pos = atomicAdd(&cursor[edst[i]], 1);
        csr_src[pos] = esrc[i];
    }
}

// ---------------- weight prep (all 4 fused) ----------------

struct PrepArg { const float* W1; const float* W2; ushort* Wt; int K; int M; };

__global__ void prep_w4_k(PrepArg p0, PrepArg p1, PrepArg p2, PrepArg p3) {
    PrepArg P = (blockIdx.y == 0) ? p0 : (blockIdx.y == 1) ? p1 : (blockIdx.y == 2) ? p2 : p3;
    int i = blockIdx.x * blockDim.x + threadIdx.x;
    int tot = 2 * P.M * P.K;
    if (i >= tot) return;
    int c = i / P.K, k = i - c * P.K;
    float v = (c < P.M) ? P.W1[(size_t)k * P.M + c] : P.W2[(size_t)k * P.M + (c - P.M)];
    P.Wt[i] = f2bf(v);
}

// ---------------- MFMA GEMM: 64x128 tile, single-buffer LDS, all-fp8 outputs ---------
// Swapped-operand MFMA (lane = 1 row x 4 consecutive cols). XCD-aware block swizzle:
// xcd = id&7, all NC col-blocks of a row-block land on the SAME XCD consecutively
// (L2-hot A re-reads). cols<M -> V8, cols>=M -> R8 (both fp8, HW cvt_pk encode).

struct GArg { const void* A; const ushort* Wt; uchar* V8; uchar* R8; };
template<int NY> struct GArgs { GArg a[NY]; };

template<bool A_FP32, int NY>
__global__ __launch_bounds__(256) void gemm_mfma_k(GArgs<NY> P, int K, int M,
                                                   int ldv, int ldr, int n) {
    __shared__ __align__(16) uchar smem[15360];  // As[64][40] + Bs[128][40]; epi C8 8448B
    ushort* As = (ushort*)smem;
    ushort* Bs = As + 64 * 40;
    const GArg& G = P.a[blockIdx.z];
    const void* __restrict__ Av = G.A;
    const ushort* __restrict__ Wt = G.Wt;

    int tid = threadIdx.x;
    int NC = (2 * M) >> 7; if (NC == 0) NC = 1;
    int RBm = (n + 63) >> 6;
    int xcd = blockIdx.x & 7;
    int q = blockIdx.x >> 3;
    int cb = q % NC;
    int rb = (q / NC) * 8 + xcd;
    if (rb >= RBm) return;
    int row0 = rb * 64;
    int col0 = cb * 128;
    int lane = tid & 63, wid = tid >> 6;
    int wm = wid & 1, wn = wid >> 1;
    int lrow = lane & 15, lko = (lane >> 4) * 8;

    f32x4 acc[2][4];
    #pragma unroll
    for (int i = 0; i < 2; ++i)
        #pragma unroll
        for (int j = 0; j < 4; ++j)
            acc[i][j] = (f32x4){0.f, 0.f, 0.f, 0.f};

    float4 fA0, fA1;
    uint4 uA, uB0, uB1;

    auto LOAD = [&](int it) {
        int kc = it << 5;
        if constexpr (A_FP32) {
            const float* A = (const float*)Av;
            int r = tid >> 3, s = tid & 7;
            int rg0 = row0 + r, rg1 = rg0 + 32;
            fA0 = (rg0 < n) ? *(const float4*)(A + (size_t)rg0 * K + kc + s * 4)
                            : make_float4(0.f, 0.f, 0.f, 0.f);
            fA1 = (rg1 < n) ? *(const float4*)(A + (size_t)rg1 * K + kc + s * 4)
                            : make_float4(0.f, 0.f, 0.f, 0.f);
        } else {
            const ushort* A = (const ushort*)Av;
            int r = tid >> 2, s = tid & 3;
            int rg = row0 + r;
            uA = (rg < n) ? *(const uint4*)(A + (size_t)rg * K + kc + s * 8)
                          : make_uint4(0u, 0u, 0u, 0u);
        }
        int rB = tid >> 2, sB = tid & 3;
        uB0 = *(const uint4*)(Wt + (size_t)(col0 + rB) * K + kc + sB * 8);
        uB1 = *(const uint4*)(Wt + (size_t)(col0 + rB + 64) * K + kc + sB * 8);
    };
    auto STORE_LDS = [&]() {
        if constexpr (A_FP32) {
            int r = tid >> 3, s = tid & 7;
            *(uint2*)(&As[r * 40 + s * 4]) =
                make_uint2(pk2bf(fA0.x, fA0.y), pk2bf(fA0.z, fA0.w));
            *(uint2*)(&As[(r + 32) * 40 + s * 4]) =
                make_uint2(pk2bf(fA1.x, fA1.y), pk2bf(fA1.z, fA1.w));
        } else {
            int r = tid >> 2, s = tid & 3;
            *(uint4*)(&As[r * 40 + s * 8]) = uA;
        }
        int rB = tid >> 2, sB = tid & 3;
        *(uint4*)(&Bs[rB * 40 + sB * 8]) = uB0;
        *(uint4*)(&Bs[(rB + 64) * 40 + sB * 8]) = uB1;
    };

    const int nIt = K >> 5;
    LOAD(0);
    for (int it = 0; it < nIt; ++it) {
        __syncthreads();
        STORE_LDS();
        __syncthreads();
        if (it + 1 < nIt) LOAD(it + 1);

        bf16x8 af[2], bfr[4];
        #pragma unroll
        for (int i = 0; i < 2; ++i)
            af[i] = *(const bf16x8*)(&As[(wm * 32 + i * 16 + lrow) * 40 + lko]);
        #pragma unroll
        for (int j = 0; j < 4; ++j)
            bfr[j] = *(const bf16x8*)(&Bs[(wn * 64 + j * 16 + lrow) * 40 + lko]);
        #pragma unroll
        for (int i = 0; i < 2; ++i)
            #pragma unroll
            for (int j = 0; j < 4; ++j)
                acc[i][j] = __builtin_amdgcn_mfma_f32_16x16x32_bf16(bfr[j], af[i], acc[i][j], 0, 0, 0);
    }

    // -------- unified fp8 packed-dword epilogue: C8dw[64][33] --------
    __syncthreads();
    uint* C8 = (uint*)smem;
    #pragma unroll
    for (int i = 0; i < 2; ++i) {
        int m = wm * 32 + i * 16 + (lane & 15);
        #pragma unroll
        for (int j = 0; j < 4; ++j) {
            int dc = wn * 16 + j * 4 + (lane >> 4);
            C8[m * 33 + dc] = pk4f8(acc[i][j][0], acc[i][j][1], acc[i][j][2], acc[i][j][3]);
        }
    }
    __syncthreads();
    int row = tid >> 2, seg = tid & 3;   // 4 segs x 32B per 128B row
    if (row0 + row < n) {
        uint w[8];
        #pragma unroll
        for (int t = 0; t < 8; ++t) w[t] = C8[row * 33 + seg * 8 + t];
        uchar* base;
        if (M >= 128) {
            base = (col0 < M) ? G.V8 + (size_t)(row0 + row) * ldv + col0 + seg * 32
                              : G.R8 + (size_t)(row0 + row) * ldr + (col0 - M) + seg * 32;
        } else {
            base = (seg < 2) ? G.V8 + (size_t)(row0 + row) * ldv + seg * 32
                             : G.R8 + (size_t)(row0 + row) * ldr + (seg - 2) * 32;
        }
        ((uint4*)base)[0] = make_uint4(w[0], w[1], w[2], w[3]);
        ((uint4*)base)[1] = make_uint4(w[4], w[5], w[6], w[7]);
    }
}

// ---------------- fused agg, 512B interleaved rows (input: NZ=4, mid: NZ=2) ----------

struct Bias4 { const float* b[4]; };

template<int NZ, int U>
__global__ __launch_bounds__(256) void agg_f512_k(const uchar* __restrict__ V8,
                                                  const uchar* __restrict__ R8,
                                                  Bias4 B,
                                                  const float* __restrict__ inv_deg,
                                                  const int* __restrict__ row_start,
                                                  const int* __restrict__ csr_src,
                                                  ushort* __restrict__ xkout,
                                                  size_t tstride, int n) {
    constexpr int LPZ = 64 / NZ;
    int wid  = (blockIdx.x * blockDim.x + threadIdx.x) >> 6;
    int lane = threadIdx.x & 63;
    if (wid >= n) return;
    int dst = wid;
    int c0 = (lane & (LPZ - 1)) * 8;
    const float* bp = B.b[lane / LPZ] + c0;
    int off8 = lane * 8;

    float acc[8];
    #pragma unroll
    for (int q = 0; q < 8; ++q) acc[q] = 0.f;

    int s = row_start[dst], e = row_start[dst + 1];
    for (int g = s; g < e; g += U) {
        int idx[U];
        #pragma unroll
        for (int u = 0; u < U; ++u)
            idx[u] = (g + u < e) ? csr_src[g + u] : -1;
        uint2 d[U];
        #pragma unroll
        for (int u = 0; u < U; ++u) {
            d[u] = make_uint2(0u, 0u);
            if (idx[u] >= 0) d[u] = *(const uint2*)(V8 + (size_t)idx[u] * 512 + off8);
        }
        #pragma unroll
        for (int u = 0; u < U; ++u) {
            acc_fp8x4(acc,     d[u].x);
            acc_fp8x4(acc + 4, d[u].y);
        }
    }

    float inv = inv_deg[dst];
    float r[8];
    #pragma unroll
    for (int q = 0; q < 8; ++q) r[q] = acc[q] * inv + bp[q];
    uint2 rr = *(const uint2*)(R8 + (size_t)dst * 512 + off8);
    acc_fp8x4(r,     rr.x);
    acc_fp8x4(r + 4, rr.y);
    #pragma unroll
    for (int q = 0; q < 8; ++q) r[q] = fmaxf(r[q], 0.f);   // relu

    uint4 o;
    o.x = pk2bf(r[0], r[1]); o.y = pk2bf(r[2], r[3]);
    o.z = pk2bf(r[4], r[5]); o.w = pk2bf(r[6], r[7]);
    *(uint4*)(xkout + (size_t)(lane >> 5) * tstride + (size_t)dst * 256 + (lane & 31) * 8) = o;
}

// ---------------- fused agg, 128B interleaved rows (out layer + head agg) ------------

template<int ACT, bool WF8, int U>
__global__ __launch_bounds__(256) void agg_f128_k(const uchar* __restrict__ V8,
                                                  const uchar* __restrict__ R8,
                                                  const float* __restrict__ bias,
                                                  const float* __restrict__ inv_deg,
                                                  const int* __restrict__ row_start,
                                                  const int* __restrict__ csr_src,
                                                  ushort* __restrict__ outb, size_t tstride,
                                                  uchar* __restrict__ out8,
                                                  int n) {
    int wid  = (blockIdx.x * blockDim.x + threadIdx.x) >> 6;
    int lane = threadIdx.x & 63;
    if (wid >= n) return;
    int dst   = wid;
    int sub   = lane & 15;
    int eslot = lane >> 4;
    int task  = sub >> 3;
    int c0    = (sub & 7) * 8;

    float acc[8];
    #pragma unroll
    for (int q = 0; q < 8; ++q) acc[q] = 0.f;

    int s = row_start[dst], e = row_start[dst + 1];
    for (int g = s; g < e; g += 4 * U) {
        int idx[U];
        #pragma unroll
        for (int u = 0; u < U; ++u) {
            int t = g + u * 4 + eslot;
            idx[u] = (t < e) ? csr_src[t] : -1;
        }
        uint2 d[U];
        #pragma unroll
        for (int u = 0; u < U; ++u) {
            d[u] = make_uint2(0u, 0u);
            if (idx[u] >= 0) d[u] = *(const uint2*)(V8 + (size_t)idx[u] * 128 + sub * 8);
        }
        #pragma unroll
        for (int u = 0; u < U; ++u) {
            acc_fp8x4(acc,     d[u].x);
            acc_fp8x4(acc + 4, d[u].y);
        }
    }

    #pragma unroll
    for (int mask = 16; mask < 64; mask <<= 1)
        #pragma unroll
        for (int q = 0; q < 8; ++q)
            acc[q] += __shfl_xor(acc[q], mask);

    if (eslot == 0) {
        float inv = inv_deg[dst];
        float r[8];
        #pragma unroll
        for (int q = 0; q < 8; ++q) r[q] = acc[q] * inv;
        if (bias) {
            #pragma unroll
            for (int q = 0; q < 8; ++q) r[q] += bias[c0 + q];
        }
        if (R8) {
            uint2 rr = *(const uint2*)(R8 + (size_t)dst * 128 + sub * 8);
            acc_fp8x4(r,     rr.x);
            acc_fp8x4(r + 4, rr.y);
        }
        #pragma unroll
        for (int q = 0; q < 8; ++q) {
            if constexpr (ACT == 2) r[q] = 1.f / (1.f + expf(-r[q]));
        }
        uint4 o;
        o.x = pk2bf(r[0], r[1]); o.y = pk2bf(r[2], r[3]);
        o.z = pk2bf(r[4], r[5]); o.w = pk2bf(r[6], r[7]);
        *(uint4*)(outb + (size_t)task * tstride + (size_t)dst * 64 + c0) = o;
        if constexpr (WF8) {
            uint2 o8;
            o8.x = pk4f8(r[0], r[1], r[2], r[3]);
            o8.y = pk4f8(r[4], r[5], r[6], r[7]);
            *(uint2*)(out8 + (size_t)dst * 128 + sub * 8) = o8;
        }
    }
}

// ---------------- heads + cross-entropy (spill-free, both tasks via blockIdx.y) ------

template<int C>
__device__ inline float ce_from_z(float* z, int label) {
    float m = -1e30f;
    #pragma unroll
    for (int c = 0; c < C; ++c) { z[c] = 1.f / (1.f + expf(-z[c])); m = fmaxf(m, z[c]); }
    float ssum = 0.f, zl = 0.f;
    #pragma unroll
    for (int c = 0; c < C; ++c) { ssum += expf(z[c] - m); if (c == label) zl = z[c]; }
    return (logf(ssum) + m) - zl;
}

__global__ __launch_bounds__(256) void head_ce_k(const ushort* __restrict__ Ah,
                                                 const ushort* __restrict__ hk,
                                                 const float* __restrict__ Wl1, const float* __restrict__ b1, const float* __restrict__ Wr1,
                                                 const float* __restrict__ Wl2, const float* __restrict__ b2, const float* __restrict__ Wr2,
                                                 const float* __restrict__ Wl3, const float* __restrict__ b3, const float* __restrict__ Wr3,
                                                 const int* __restrict__ yv,
                                                 float* __restrict__ loss_acc, int n) {
    int ty = blockIdx.y;
    int nidx = blockIdx.x * blockDim.x + threadIdx.x;
    Wl1 += ty * 64 * 12; b1 += ty * 12; Wr1 += ty * 64 * 12;
    Wl2 += ty * 64 * 8;  b2 += ty * 8;  Wr2 += ty * 64 * 8;
    Wl3 += ty * 64 * 5;  b3 += ty * 5;  Wr3 += ty * 64 * 5;
    float lsum = 0.f;
    if (nidx < n) {
        float z0[12], z1[8], z2[5];
        #pragma unroll
        for (int c = 0; c < 12; ++c) z0[c] = b1[c];
        #pragma unroll
        for (int c = 0; c < 8; ++c) z1[c] = b2[c];
        #pragma unroll
        for (int c = 0; c < 5; ++c) z2[c] = b3[c];

        const ushort* ap = Ah + ((size_t)ty * NN + nidx) * 64;
        const ushort* hp = hk + ((size_t)ty * NN + nidx) * 64;
        for (int d8 = 0; d8 < 64; d8 += 8) {
            uint4 ua = *(const uint4*)(ap + d8);
            uint4 uh = *(const uint4*)(hp + d8);
            uint aw[4] = {ua.x, ua.y, ua.z, ua.w};
            uint hw[4] = {uh.x, uh.y, uh.z, uh.w};
            #pragma unroll
            for (int p = 0; p < 4; ++p) {
                #pragma unroll
                for (int half = 0; half < 2; ++half) {
                    int d = d8 + p * 2 + half;
                    float av = bf2f((ushort)(half ? (aw[p] >> 16) : (aw[p] & 0xFFFF)));
                    float hv = bf2f((ushort)(half ? (hw[p] >> 16) : (hw[p] & 0xFFFF)));
                    #pragma unroll
                    for (int c = 0; c < 12; ++c)
                        z0[c] = fmaf(av, Wl1[d * 12 + c], fmaf(hv, Wr1[d * 12 + c], z0[c]));
                    #pragma unroll
                    for (int c = 0; c < 8; ++c)
                        z1[c] = fmaf(av, Wl2[d * 8 + c], fmaf(hv, Wr2[d * 8 + c], z1[c]));
                    #pragma unroll
                    for (int c = 0; c < 5; ++c)
                        z2[c] = fmaf(av, Wl3[d * 5 + c], fmaf(hv, Wr3[d * 5 + c], z2[c]));
                }
            }
        }
        const int* yp = yv + ((size_t)ty * NN + nidx) * 3;
        lsum  = ce_from_z<12>(z0, yp[0]);
        lsum += ce_from_z<8 >(z1, yp[1]);
        lsum += ce_from_z<5 >(z2, yp[2]);
    }
    for (int off = 32; off > 0; off >>= 1) lsum += __shfl_down(lsum, off);
    __shared__ float ssum[4];
    int wv = threadIdx.x >> 6, ln = threadIdx.x & 63;
    if (ln == 0) ssum[wv] = lsum;
    __syncthreads();
    if (threadIdx.x == 0) atomicAdd(loss_acc, ssum[0] + ssum[1] + ssum[2] + ssum[3]);
}

__global__ void finalize_k(const float* __restrict__ loss_acc, float* __restrict__ out, int n) {
    out[0] = loss_acc[0] * (1.0f / (float)n);
}

// ---------------- host ----------------

extern "C" void kernel_launch(void* const* d_in, const int* in_sizes, int n_in,
                              void* d_out, int out_size, void* d_ws, size_t ws_size,
                              hipStream_t stream) {
    const float* X    = (const float*)d_in[0];
    const int*   esrc = (const int*)d_in[1];
    const int*   edst = (const int*)d_in[2];
    const int*   y    = (const int*)d_in[3];
    const float* Wl_i[2] = {(const float*)d_in[4], (const float*)d_in[7]};
    const float* bl_i[2] = {(const float*)d_in[5], (const float*)d_in[8]};
    const float* Wr_i[2] = {(const float*)d_in[6], (const float*)d_in[9]};
    const float* Wl_m = (const float*)d_in[10], *bl_m = (const float*)d_in[11], *Wr_m = (const float*)d_in[12];
    const float* Wl_o = (const float*)d_in[13], *bl_o = (const float*)d_in[14], *Wr_o = (const float*)d_in[15];
    const float* Wl_t1 = (const float*)d_in[16], *bl_t1 = (const float*)d_in[17], *Wr_t1 = (const float*)d_in[18];
    const float* Wl_t2 = (const float*)d_in[19], *bl_t2 = (const float*)d_in[20], *Wr_t2 = (const float*)d_in[21];
    const float* Wl_t3 = (const float*)d_in[22], *bl_t3 = (const float*)d_in[23], *Wr_t3 = (const float*)d_in[24];

    const int N = NN, E = NE;
    char* p = (char*)d_ws;
    auto alloc = [&](size_t bytes) -> char* {
        char* r = p;
        p += (bytes + 255) & ~(size_t)255;
        return r;
    };
    int*    counts    = (int*)alloc((size_t)N * 4);
    int*    row_start = (int*)alloc((size_t)(N + 1) * 4);
    int*    cursor    = (int*)alloc((size_t)N * 4);
    int*    bsum      = (int*)alloc(64 * 4);
    int*    csr_src   = (int*)alloc((size_t)E * 4);
    float*  inv_deg   = (float*)alloc((size_t)N * 4);
    float*  loss_acc  = (float*)alloc(256);
    uchar*  V8i  = (uchar*)alloc((size_t)N * 512);            // [n][4*128] fp8
    uchar*  Ri8  = (uchar*)alloc((size_t)N * 512);            // [n][4*128] fp8
    uchar*  V8m  = (uchar*)alloc((size_t)N * 512);            // [n][2*256] fp8
    uchar*  Rm8  = (uchar*)alloc((size_t)N * 512);            // [n][2*256] fp8
    uchar*  V8o  = (uchar*)alloc((size_t)N * 128);            // [n][2*64] fp8
    uchar*  Ro8  = (uchar*)alloc((size_t)N * 128);            // [n][2*64] fp8
    ushort* xk   = (ushort*)alloc((size_t)2 * N * 256 * 2);   // [2][n][256] bf16
    ushort* hk   = (ushort*)alloc((size_t)2 * N * 64 * 2);    // [2][n][64] bf16
    uchar*  hk8  = (uchar*)alloc((size_t)N * 128);            // [n][2*64] fp8
    ushort* Ah   = (ushort*)alloc((size_t)2 * N * 64 * 2);    // [2][n][64] bf16
    ushort* Wt_i0 = (ushort*)alloc((size_t)256 * 128 * 2);
    ushort* Wt_i1 = (ushort*)alloc((size_t)256 * 128 * 2);
    ushort* Wt_m  = (ushort*)alloc((size_t)512 * 256 * 2);
    ushort* Wt_o  = (ushort*)alloc((size_t)128 * 256 * 2);

    hipMemsetAsync(counts, 0, (size_t)N * 4, stream);
    hipMemsetAsync(loss_acc, 0, 4, stream);
    count_edges_k<<<(E + 255) / 256, 256, 0, stream>>>(edst, counts, E);
    const int NB = (N + 1023) / 1024;
    scan1_k<<<NB, 1024, 0, stream>>>(counts, row_start, bsum, N);
    scan2_k<<<1, 64, 0, stream>>>(bsum, NB);
    scan3_k<<<(N + 255) / 256, 256, 0, stream>>>(counts, bsum, row_start, cursor, inv_deg, N, E);
    fill_csr_k<<<(E + 255) / 256, 256, 0, stream>>>(esrc, edst, cursor, csr_src, E);

    {
        PrepArg p0 = {Wl_i[0], Wr_i[0], Wt_i0, 128, 128};
        PrepArg p1 = {Wl_i[1], Wr_i[1], Wt_i1, 128, 128};
        PrepArg p2 = {Wl_m, Wr_m, Wt_m, 256, 256};
        PrepArg p3 = {Wl_o, Wr_o, Wt_o, 256, 64};
        prep_w4_k<<<dim3(512, 4), 256, 0, stream>>>(p0, p1, p2, p3);
    }

    const int RBp = (((N + 63) / 64 + 7) / 8) * 8;   // row blocks padded to 8 (XCD swizzle)
    const int AGB = (N + 3) / 4;
    const ushort* Wt_i[2] = {Wt_i0, Wt_i1};
    const size_t TSX = (size_t)N * 256;
    const size_t TSH = (size_t)N * 64;

    // ---- stage A: input GEMMs, all 4 (k,ch) — XCD-swizzled 1D grid ----
    {
        GArgs<4> P;
        for (int z = 0; z < 4; ++z)
            P.a[z] = {X + (size_t)z * N * 128, Wt_i[z & 1], V8i + z * 128, Ri8 + z * 128};
        gemm_mfma_k<true, 4><<<dim3(RBp * 2, 1, 4), 256, 0, stream>>>(P, 128, 128, 512, 512, N);
    }
    // ---- stage B: fused input agg (U=8) ----
    {
        Bias4 B = {{bl_i[0], bl_i[1], bl_i[0], bl_i[1]}};
        agg_f512_k<4, 8><<<AGB, 256, 0, stream>>>(V8i, Ri8, B, inv_deg, row_start, csr_src,
                                                  xk, TSX, N);
    }
    // ---- stage C: mid GEMMs, both tasks ----
    {
        GArgs<2> P;
        for (int k = 0; k < 2; ++k)
            P.a[k] = {xk + (size_t)k * TSX, Wt_m, V8m + k * 256, Rm8 + k * 256};
        gemm_mfma_k<false, 2><<<dim3(RBp * 4, 1, 2), 256, 0, stream>>>(P, 256, 256, 512, 512, N);
    }
    // ---- stage D: fused mid agg (U=8) ----
    {
        Bias4 B = {{bl_m, bl_m, nullptr, nullptr}};
        agg_f512_k<2, 8><<<AGB, 256, 0, stream>>>(V8m, Rm8, B, inv_deg, row_start, csr_src,
                                                  xk, TSX, N);
    }
    // ---- stage E: out GEMMs ----
    {
        GArgs<2> P;
        for (int k = 0; k < 2; ++k)
            P.a[k] = {xk + (size_t)k * TSX, Wt_o, V8o + k * 64, Ro8 + k * 64};
        gemm_mfma_k<false, 2><<<dim3(RBp, 1, 2), 256, 0, stream>>>(P, 256, 64, 128, 128, N);
    }
    // ---- stage F: fused out agg (sigmoid, U=4) -> hk, hk8 ----
    agg_f128_k<2, true, 4><<<AGB, 256, 0, stream>>>(V8o, Ro8, bl_o, inv_deg, row_start, csr_src,
                                                    hk, TSH, hk8, N);
    // ---- stage G: fused head agg (mean of hk, U=4) -> Ah ----
    agg_f128_k<0, false, 4><<<AGB, 256, 0, stream>>>(hk8, nullptr, nullptr, inv_deg, row_start, csr_src,
                                                     Ah, TSH, nullptr, N);
    // ---- stage H: heads + CE, both tasks ----
    head_ce_k<<<dim3((N + 255) / 256, 2), 256, 0, stream>>>(Ah, hk,
        Wl_t1, bl_t1, Wr_t1, Wl_t2, bl_t2, Wr_t2, Wl_t3, bl_t3, Wr_t3,
        y, loss_acc, N);

    finalize_k<<<1, 1, 0, stream>>>(loss_acc, (float*)d_out, N);
}